// Round 12
// baseline (1275.073 us; speedup 1.0000x reference)
//
#include <hip/hip_runtime.h>
#include <hip/hip_bf16.h>

typedef __hip_bfloat16 bf16_t;
typedef __bf16 bf16x8_t __attribute__((ext_vector_type(8)));
typedef float f32x4_t __attribute__((ext_vector_type(4)));

// ---------------- workspace layout (bytes) ----------------
#define OFF_X     ((size_t)0)          // 8192*512  f32  = 16,777,216
#define OFF_XB    ((size_t)16777216)   // 8192*512  bf16 =  8,388,608
#define OFF_H1    ((size_t)25165824)   // 8192*1024 bf16 = 16,777,216
#define OFF_XN    ((size_t)41943040)   // 8192*512  bf16 =  8,388,608
#define OFF_HEADB ((size_t)50331648)   // 32000*512 bf16 = 32,768,000
#define OFF_W1B   ((size_t)83099648)   // 1024*1536 bf16 =  3,145,728
#define OFF_W2B   ((size_t)86245376)   // 512*1024  bf16 =  1,048,576
#define OFF_EW1   ((size_t)87293952)   // 64*512    bf16 =     65,536
#define OFF_ENT   ((size_t)87359488)   // 8192 f32
#define OFF_CW    ((size_t)87392256)   // 8192 f32
#define OFF_HC    ((size_t)87425024)   // 1024 f32
#define OFF_B1    ((size_t)87431168)   // 1024 f32

__device__ __forceinline__ float gelu_f(float v) {
    return 0.5f * v * (1.0f + erff(v * 0.7071067811865475f));
}

__device__ __forceinline__ void load_lds16(const bf16_t* g, bf16_t* l) {
    __builtin_amdgcn_global_load_lds(
        (const __attribute__((address_space(1))) void*)g,
        (__attribute__((address_space(3))) void*)l, 16, 0, 0);
}

#define BAR()    __builtin_amdgcn_s_barrier()
#define SCHED0() __builtin_amdgcn_sched_barrier(0)
#define LGKM0()  asm volatile("s_waitcnt lgkmcnt(0)" ::: "memory")
#define WAITV0() asm volatile("s_waitcnt vmcnt(0)" ::: "memory")
#define WAITV2() asm volatile("s_waitcnt vmcnt(2)" ::: "memory")
#define WAITV4() asm volatile("s_waitcnt vmcnt(4)" ::: "memory")

// ---------------- f32 -> bf16 convert helper ----------------
__device__ __forceinline__ void cvt_store(const float4 v, __hip_bfloat162* dst) {
    __hip_bfloat162 p0, p1;
    p0.x = __float2bfloat16(v.x); p0.y = __float2bfloat16(v.y);
    p1.x = __float2bfloat16(v.z); p1.y = __float2bfloat16(v.w);
    dst[0] = p0; dst[1] = p1;
}

// ======= fused prologue A: [cvt3 (2080) | embed (4096) | prep1 (4)] = 6180 blocks =======
__global__ void pro_a_kernel(const float* __restrict__ cn_w1, const float* __restrict__ cn_w2,
                             const float* __restrict__ ent_w1,
                             bf16_t* __restrict__ w1b, bf16_t* __restrict__ w2b,
                             bf16_t* __restrict__ ew1b,
                             const int* __restrict__ tokens, const float* __restrict__ ew,
                             const float* __restrict__ pw, float* __restrict__ x,
                             bf16_t* __restrict__ xb,
                             const float* __restrict__ cs, const float* __restrict__ ctc_w1,
                             const float* __restrict__ ctc_b1, float* __restrict__ hc) {
    int bid = blockIdx.x;
    if (bid < 1536) {            // w1b: 1024 rows x first 1536 cols of cn_w1 (ld 2048)
        int idx = bid * 256 + threadIdx.x;
        int k4 = idx % 384;
        int o = idx / 384;
        float4 v = ((const float4*)(cn_w1 + (size_t)o * 2048))[k4];
        cvt_store(v, (__hip_bfloat162*)w1b + idx * 2);
    } else if (bid < 2048) {     // w2b: 512*1024 dense
        int idx = (bid - 1536) * 256 + threadIdx.x;
        float4 v = ((const float4*)cn_w2)[idx];
        cvt_store(v, (__hip_bfloat162*)w2b + idx * 2);
    } else if (bid < 2080) {     // ew1b: 64*512 dense
        int idx = (bid - 2048) * 256 + threadIdx.x;
        float4 v = ((const float4*)ent_w1)[idx];
        cvt_store(v, (__hip_bfloat162*)ew1b + idx * 2);
    } else if (bid < 6176) {     // embed: 8192*128 quads
        int idx = (bid - 2080) * 256 + threadIdx.x;
        int d4 = idx & 127;
        int bt = idx >> 7;
        int t = bt & 1023;
        int tok = tokens[bt];
        float4 e = ((const float4*)(ew + (size_t)tok * 512))[d4];
        float4 p = ((const float4*)(pw + (size_t)t * 512))[d4];
        float4 o = make_float4(e.x + p.x, e.y + p.y, e.z + p.z, e.w + p.w);
        ((float4*)x)[idx] = o;
        __hip_bfloat162 p0, p1;
        p0.x = __float2bfloat16(o.x); p0.y = __float2bfloat16(o.y);
        p1.x = __float2bfloat16(o.z); p1.y = __float2bfloat16(o.w);
        ((__hip_bfloat162*)xb)[idx * 2]     = p0;
        ((__hip_bfloat162*)xb)[idx * 2 + 1] = p1;
    } else {                     // prep1: 1024 outputs
        int o = (bid - 6176) * 256 + threadIdx.x;
        const float* wr = ctc_w1 + (size_t)o * 512;
        float acc = 0.f;
        for (int k = 0; k < 512; k += 4) {
            float4 w4 = *(const float4*)(wr + k);
            float4 a = *(const float4*)(cs + k);
            float4 b = *(const float4*)(cs + 512 + k);
            float4 c = *(const float4*)(cs + 1024 + k);
            float4 d = *(const float4*)(cs + 1536 + k);
            acc += w4.x * (a.x + b.x + c.x + d.x) * 0.25f;
            acc += w4.y * (a.y + b.y + c.y + d.y) * 0.25f;
            acc += w4.z * (a.z + b.z + c.z + d.z) * 0.25f;
            acc += w4.w * (a.w + b.w + c.w + d.w) * 0.25f;
        }
        hc[o] = gelu_f(acc + ctc_b1[o]);
    }
}

// ======= prep2+prep3 merged: one block, 1024 threads =======
__global__ __launch_bounds__(1024) void prep23_kernel(
        const float* __restrict__ hc, const float* __restrict__ ctc_w2,
        const float* __restrict__ ctc_b2, const float* __restrict__ cn_w1,
        const float* __restrict__ cn_b1, float* __restrict__ bias1) {
    __shared__ float cc_s[512];
    int o = threadIdx.x;
    if (o < 512) {
        const float* wr = ctc_w2 + (size_t)o * 1024;
        float acc = 0.f;
        for (int k = 0; k < 1024; ++k) acc += wr[k] * hc[k];
        cc_s[o] = acc + ctc_b2[o];
    }
    __syncthreads();
    const float* wr = cn_w1 + (size_t)o * 2048 + 1536;
    float acc = 0.f;
    for (int k = 0; k < 512; ++k) acc += wr[k] * cc_s[k];
    bias1[o] = acc + cn_b1[o];
}

// ---------------- entropy MLP via MFMA: 16 tokens per wave (R4 exact) ----------------
__global__ __launch_bounds__(256) void entropy_mfma(
        const bf16_t* __restrict__ xb, const bf16_t* __restrict__ w1b,
        const float* __restrict__ b1, const float* __restrict__ w2,
        const float* __restrict__ b2, float* __restrict__ ent) {
    int wave = threadIdx.x >> 6, lane = threadIdx.x & 63;
    int lr = lane & 15, kq = lane >> 4;
    int tok0 = (blockIdx.x * 4 + wave) * 16;
    f32x4_t acc[4] = {};
    const bf16_t* xr = xb + (size_t)(tok0 + lr) * 512 + kq * 8;
    const bf16_t* wr = w1b + (size_t)lr * 512 + kq * 8;
    #pragma unroll 4
    for (int k0 = 0; k0 < 512; k0 += 32) {
        bf16x8_t a = *(const bf16x8_t*)(xr + k0);
        #pragma unroll
        for (int j = 0; j < 4; ++j) {
            bf16x8_t bb = *(const bf16x8_t*)(wr + (size_t)j * 16 * 512 + k0);
            acc[j] = __builtin_amdgcn_mfma_f32_16x16x32_bf16(a, bb, acc[j], 0, 0, 0);
        }
    }
    float p[4];
    #pragma unroll
    for (int r = 0; r < 4; ++r) {
        float s = 0.f;
        #pragma unroll
        for (int j = 0; j < 4; ++j) {
            int n = j * 16 + lr;
            s += gelu_f(acc[j][r] + b1[n]) * w2[n];
        }
        #pragma unroll
        for (int o = 1; o < 16; o <<= 1) s += __shfl_xor(s, o);
        p[r] = s;
    }
    if (lr == 0) {
        float bb = b2[0];
        #pragma unroll
        for (int r = 0; r < 4; ++r) ent[tok0 + kq * 4 + r] = p[r] + bb;
    }
}

// ======= fused epilogue: [cvt headb (16000) | ln (2048)] = 18048 blocks =======
__global__ void epi_kernel(const float* __restrict__ head_w, bf16_t* __restrict__ headb,
                           const float* __restrict__ x, const float* __restrict__ g,
                           const float* __restrict__ b, bf16_t* __restrict__ xn) {
    int bid = blockIdx.x;
    if (bid < 16000) {           // headb convert: 32000*512/4 quads
        int idx = bid * 256 + threadIdx.x;
        float4 v = ((const float4*)head_w)[idx];
        cvt_store(v, (__hip_bfloat162*)headb + idx * 2);
        return;
    }
    // LayerNorm: one wave per token
    int token = (bid - 16000) * 4 + (threadIdx.x >> 6);
    int l = threadIdx.x & 63;
    const float* xr = x + (size_t)token * 512;
    float4 v0 = ((const float4*)xr)[l * 2];
    float4 v1 = ((const float4*)xr)[l * 2 + 1];
    float s = v0.x + v0.y + v0.z + v0.w + v1.x + v1.y + v1.z + v1.w;
    float ss = v0.x * v0.x + v0.y * v0.y + v0.z * v0.z + v0.w * v0.w
             + v1.x * v1.x + v1.y * v1.y + v1.z * v1.z + v1.w * v1.w;
    #pragma unroll
    for (int o = 32; o; o >>= 1) { s += __shfl_xor(s, o); ss += __shfl_xor(ss, o); }
    float mu = s * (1.0f / 512.0f);
    float var = ss * (1.0f / 512.0f) - mu * mu;
    float rs = rsqrtf(var + 1e-5f);
    float4 g0 = ((const float4*)g)[l * 2], g1 = ((const float4*)g)[l * 2 + 1];
    float4 b0 = ((const float4*)b)[l * 2], b1 = ((const float4*)b)[l * 2 + 1];
    bf16_t* op = xn + (size_t)token * 512 + l * 8;
    op[0] = __float2bfloat16((v0.x - mu) * rs * g0.x + b0.x);
    op[1] = __float2bfloat16((v0.y - mu) * rs * g0.y + b0.y);
    op[2] = __float2bfloat16((v0.z - mu) * rs * g0.z + b0.z);
    op[3] = __float2bfloat16((v0.w - mu) * rs * g0.w + b0.w);
    op[4] = __float2bfloat16((v1.x - mu) * rs * g1.x + b1.x);
    op[5] = __float2bfloat16((v1.y - mu) * rs * g1.y + b1.y);
    op[6] = __float2bfloat16((v1.z - mu) * rs * g1.z + b1.z);
    op[7] = __float2bfloat16((v1.w - mu) * rs * g1.w + b1.w);
}

// ================= 8-phase 256xBN bf16 MFMA GEMM (R4-exact; MODE2 nt-stores) =======
// FUSE_SM: blocks [0,8) run the per-batch softmax (R11 refcheck'd variant).
template <int MODE, int ROLL, int BN, int FUSE_SM>
__global__ __launch_bounds__(512, 2) void gemm8p(
    const bf16_t* __restrict__ A, int lda,
    const bf16_t* __restrict__ B, int ldb, int K, int NMT, int ngemm,
    const float* __restrict__ bias,
    bf16_t* __restrict__ out_bf, int ldc,
    const float* __restrict__ cw, float* __restrict__ x,
    float* __restrict__ out_f,
    const float* __restrict__ entp, const float* __restrict__ btp,
    float stepf, float* __restrict__ cwout)
{
    constexpr int JJ = BN / 64;                 // B-frags per wave per kk (4 or 2)
    __shared__ __align__(16) bf16_t As[2][256 * 64];
    __shared__ __align__(16) bf16_t Bs[2][BN * 64];
    __shared__ float sred[8];
    __shared__ float sbc[2];

    const int tid = threadIdx.x;
    const int wave = tid >> 6, lane = tid & 63;

    if (FUSE_SM && (int)blockIdx.x < 8) {
        const float* eb = entp + (size_t)blockIdx.x * 1024;
        float bt = btp[0];
        float sp = (bt > 20.0f) ? bt : log1pf(expf(bt));
        float inv = -1.0f / (sp * stepf);
        float v0 = eb[tid] * inv;
        float v1 = eb[tid + 512] * inv;
        float mx = fmaxf(v0, v1);
        #pragma unroll
        for (int o = 32; o; o >>= 1) mx = fmaxf(mx, __shfl_xor(mx, o));
        if (lane == 0) sred[wave] = mx;
        __syncthreads();
        if (tid < 64) {
            float mm = (tid < 8) ? sred[tid] : -3.4e38f;
            #pragma unroll
            for (int o = 4; o; o >>= 1) mm = fmaxf(mm, __shfl_xor(mm, o));
            if (tid == 0) sbc[0] = mm;
        }
        __syncthreads();
        float M = sbc[0];
        float e0 = expf(v0 - M), e1 = expf(v1 - M);
        float s = e0 + e1;
        #pragma unroll
        for (int o = 32; o; o >>= 1) s += __shfl_xor(s, o);
        if (lane == 0) sred[wave] = s;
        __syncthreads();
        if (tid < 64) {
            float ssum = (tid < 8) ? sred[tid] : 0.f;
            #pragma unroll
            for (int o = 4; o; o >>= 1) ssum += __shfl_xor(ssum, o);
            if (tid == 0) sbc[1] = ssum;
        }
        __syncthreads();
        float S = sbc[1];
        cwout[blockIdx.x * 1024 + tid]       = e0 / S;
        cwout[blockIdx.x * 1024 + tid + 512] = e1 / S;
        return;
    }

    const int NT = K >> 6;
    const int id0 = (int)blockIdx.x - (FUSE_SM ? 8 : 0);
    const int id = (id0 & 7) * (ngemm >> 3) + (id0 >> 3);  // bijective XCD swizzle (ngemm%8==0)
    const int m0 = (id % NMT) * 256;
    const int n0 = (id / NMT) * BN;

    const int wm = (wave >> 2) * 128;
    const int wn = (wave & 3) * (BN / 4);
    const int lr = lane & 15, kq = lane >> 4;

    const int swz0 = (kq)     ^ (lr & 7);
    const int swz1 = (4 + kq) ^ (lr & 7);
    const int eoff0 = lr * 64 + swz0 * 8;
    const int eoff1 = lr * 64 + swz1 * 8;

    const int u0row = tid >> 3;                 // 0..63
    const int u1row = 64 + (tid >> 3);          // 64..127
    const int usl   = tid & 7;
    const int c0 = ((usl ^ (u0row & 7)) * 8);
    const int c1 = ((usl ^ (u1row & 7)) * 8);

    f32x4_t acc[8][JJ] = {};
    bf16x8_t bfr[JJ][2];

    auto stageA = [&](int ktile, int c, int half) {
        const int kbase = ktile << 6;
        const int r0 = m0 + half * 128 + u0row;
        const int r1 = m0 + half * 128 + u1row;
        const bf16_t *g0, *g1;
        if (ROLL) {
            const int seg = kbase >> 9;
            const int kk2 = kbase & 511;
            const int sh = (seg == 0) ? 0 : ((seg == 1) ? 1023 : 1);
            const int s0 = (r0 & ~1023) | (((r0 & 1023) + sh) & 1023);
            const int s1 = (r1 & ~1023) | (((r1 & 1023) + sh) & 1023);
            g0 = A + (size_t)s0 * 512 + kk2 + c0;
            g1 = A + (size_t)s1 * 512 + kk2 + c1;
        } else {
            g0 = A + (size_t)r0 * lda + kbase + c0;
            g1 = A + (size_t)r1 * lda + kbase + c1;
        }
        bf16_t* l = &As[c][half * 128 * 64];
        load_lds16(g0, l + tid * 8);
        load_lds16(g1, l + (tid + 512) * 8);
    };
    auto stageB = [&](int ktile, int c, int half) {
        const int kbase = ktile << 6;
        const int r0 = n0 + half * 128 + u0row;
        const int r1 = n0 + half * 128 + u1row;
        const bf16_t* g0 = B + (size_t)r0 * ldb + kbase + c0;
        const bf16_t* g1 = B + (size_t)r1 * ldb + kbase + c1;
        bf16_t* l = &Bs[c][half * 128 * 64];
        load_lds16(g0, l + tid * 8);
        load_lds16(g1, l + (tid + 512) * 8);
    };

    // ---- prologue: A(0), B(0) resident; B(1) in flight ----
    stageA(0, 0, 0); stageA(0, 0, 1);
    stageB(0, 0, 0); if (BN == 256) stageB(0, 0, 1);
    stageB(1, 1, 0); if (BN == 256) stageB(1, 1, 1);
    if (BN == 256) { WAITV4(); } else { WAITV2(); }
    BAR();

    int cur = 0;
    for (int t = 0; t < NT; ++t) {
        #pragma unroll
        for (int p = 0; p < 4; ++p) {
            bf16x8_t af0k0, af0k1, af1k0, af1k1;
            {
                const int r0 = (wm + 32 * p + lr) * 64;
                const int r1 = (wm + 32 * p + 16 + lr) * 64;
                af0k0 = *(const bf16x8_t*)&As[cur][r0 - lr * 64 + eoff0];
                af0k1 = *(const bf16x8_t*)&As[cur][r0 - lr * 64 + eoff1];
                af1k0 = *(const bf16x8_t*)&As[cur][r1 - lr * 64 + eoff0];
                af1k1 = *(const bf16x8_t*)&As[cur][r1 - lr * 64 + eoff1];
            }
            if (p == 0) {
                #pragma unroll
                for (int j = 0; j < JJ; ++j) {
                    const int rb = (wn + 16 * j) * 64;
                    bfr[j][0] = *(const bf16x8_t*)&Bs[cur][rb + eoff0];
                    bfr[j][1] = *(const bf16x8_t*)&Bs[cur][rb + eoff1];
                }
            }
            if (p == 0 && t + 1 < NT) stageA(t + 1, cur ^ 1, 0);
            if (p == 1 && t + 1 < NT) stageA(t + 1, cur ^ 1, 1);
            if (p == 2 && t + 2 < NT) stageB(t + 2, cur, 0);
            if (p == 3 && BN == 256 && t + 2 < NT) stageB(t + 2, cur, 1);

            BAR();
            LGKM0();
            SCHED0();
            __builtin_amdgcn_s_setprio(1);
            #pragma unroll
            for (int j = 0; j < JJ; ++j) {
                acc[2*p][j]   = __builtin_amdgcn_mfma_f32_16x16x32_bf16(af0k0, bfr[j][0], acc[2*p][j],   0, 0, 0);
                acc[2*p+1][j] = __builtin_amdgcn_mfma_f32_16x16x32_bf16(af1k0, bfr[j][0], acc[2*p+1][j], 0, 0, 0);
            }
            #pragma unroll
            for (int j = 0; j < JJ; ++j) {
                acc[2*p][j]   = __builtin_amdgcn_mfma_f32_16x16x32_bf16(af0k1, bfr[j][1], acc[2*p][j],   0, 0, 0);
                acc[2*p+1][j] = __builtin_amdgcn_mfma_f32_16x16x32_bf16(af1k1, bfr[j][1], acc[2*p+1][j], 0, 0, 0);
            }
            __builtin_amdgcn_s_setprio(0);
            SCHED0();
            if (p == 3) {
                if (t + 2 < NT) { if (BN == 256) { WAITV4(); } else { WAITV2(); } }
                else           { WAITV0(); }
            }
            BAR();
        }
        cur ^= 1;
    }

    // ---- epilogue ----
    #pragma unroll
    for (int i = 0; i < 8; ++i) {
        const int rbase = m0 + wm + i * 16 + kq * 4;   // C/D: row=(lane>>4)*4+reg
        #pragma unroll
        for (int j = 0; j < JJ; ++j) {
            const int gcol = n0 + wn + j * 16 + lr;    // C/D: col=lane&15
            #pragma unroll
            for (int r = 0; r < 4; ++r) {
                const size_t grow = (size_t)(rbase + r);
                float v = acc[i][j][r];
                if (MODE == 0) {
                    v = gelu_f(v + bias[gcol]);
                    out_bf[grow * ldc + gcol] = __float2bfloat16(v);
                } else if (MODE == 1) {
                    v += bias[gcol];
                    float nv = x[grow * ldc + gcol] + v * cw[grow] * 0.3f;
                    x[grow * ldc + gcol] = nv;
                    out_bf[grow * ldc + gcol] = __float2bfloat16(nv);
                } else {
                    // write-once 1.05 GB stream: bypass caches (R10: -79 us)
                    __builtin_nontemporal_store(v, &out_f[grow * ldc + gcol]);
                }
            }
        }
    }
}

extern "C" void kernel_launch(void* const* d_in, const int* in_sizes, int n_in,
                              void* d_out, int out_size, void* d_ws, size_t ws_size,
                              hipStream_t stream) {
    const int*   tokens   = (const int*)d_in[0];
    const float* c_states = (const float*)d_in[1];
    const float* embed_w  = (const float*)d_in[2];
    const float* pos_w    = (const float*)d_in[3];
    const float* cn_w1    = (const float*)d_in[4];
    const float* cn_b1    = (const float*)d_in[5];
    const float* cn_w2    = (const float*)d_in[6];
    const float* cn_b2    = (const float*)d_in[7];
    const float* ent_w1   = (const float*)d_in[8];
    const float* ent_b1   = (const float*)d_in[9];
    const float* ent_w2   = (const float*)d_in[10];
    const float* ent_b2   = (const float*)d_in[11];
    const float* ctc_w1   = (const float*)d_in[12];
    const float* ctc_b1   = (const float*)d_in[13];
    const float* ctc_w2   = (const float*)d_in[14];
    const float* ctc_b2   = (const float*)d_in[15];
    const float* base_temp= (const float*)d_in[16];
    const float* ln_g     = (const float*)d_in[17];
    const float* ln_b     = (const float*)d_in[18];
    const float* head_w   = (const float*)d_in[19];
    float* out = (float*)d_out;

    char* ws = (char*)d_ws;
    float*  x     = (float*)(ws + OFF_X);
    bf16_t* xb    = (bf16_t*)(ws + OFF_XB);
    bf16_t* h1    = (bf16_t*)(ws + OFF_H1);
    bf16_t* xn    = (bf16_t*)(ws + OFF_XN);
    bf16_t* headb = (bf16_t*)(ws + OFF_HEADB);
    bf16_t* w1b   = (bf16_t*)(ws + OFF_W1B);
    bf16_t* w2b   = (bf16_t*)(ws + OFF_W2B);
    bf16_t* ew1b  = (bf16_t*)(ws + OFF_EW1);
    float*  ent   = (float*)(ws + OFF_ENT);
    float*  cw    = (float*)(ws + OFF_CW);
    float*  hc    = (float*)(ws + OFF_HC);
    float*  bias1 = (float*)(ws + OFF_B1);

    // fused prologue: [cvt3 | embed | prep1]; then merged prep2+prep3
    pro_a_kernel<<<6180, 256, 0, stream>>>(cn_w1, cn_w2, ent_w1, w1b, w2b, ew1b,
                                           tokens, embed_w, pos_w, x, xb,
                                           c_states, ctc_w1, ctc_b1, hc);
    prep23_kernel<<<1, 1024, 0, stream>>>(hc, ctc_w2, ctc_b2, cn_w1, cn_b1, bias1);

    for (int step = 0; step < 6; ++step) {
        float stepf = 1.0f - ((float)step / 6.0f) * 0.8f;
        entropy_mfma<<<128, 256, 0, stream>>>(xb, ew1b, ent_b1, ent_w2, ent_b2, ent);
        // gemm1 + fused softmax: 256x256 tiles (proven BN=256 path), 8 + 128 = 136 blocks
        gemm8p<0, 1, 256, 1><<<136, 512, 0, stream>>>(
            xb, 512, w1b, 1536, 1536, 32, 128,
            bias1, h1, 1024, nullptr, nullptr, nullptr,
            ent, base_temp, stepf, cw);
        // gemm2: [8192x1024]x[512x1024]^T, 256x128 tiles -> 128 blocks (unchanged)
        gemm8p<1, 0, 128, 0><<<128, 512, 0, stream>>>(
            h1, 1024, w2b, 1024, 1024, 32, 128,
            cn_b2, xb, 512, cw, x, nullptr,
            nullptr, nullptr, 0.f, nullptr);
    }

    // fused epilogue: [cvt headb | ln]
    epi_kernel<<<18048, 256, 0, stream>>>(head_w, headb, x, ln_g, ln_b, xn);
    // head: [8192x512]x[32000x512]^T, 256x256 tiles -> 4000 blocks
    gemm8p<2, 0, 256, 0><<<4000, 512, 0, stream>>>(
        xn, 512, headb, 512, 512, 32, 4000,
        nullptr, nullptr, 32000, nullptr, nullptr, out,
        nullptr, nullptr, 0.f, nullptr);
}

// Round 14
// 1201.349 us; speedup vs baseline: 1.0614x; 1.0614x over previous
//
#include <hip/hip_runtime.h>
#include <hip/hip_bf16.h>

typedef __hip_bfloat16 bf16_t;
typedef __bf16 bf16x8_t __attribute__((ext_vector_type(8)));
typedef float f32x4_t __attribute__((ext_vector_type(4)));

// ---------------- workspace layout (bytes) ----------------
#define OFF_X     ((size_t)0)          // 8192*512  f32  = 16,777,216
#define OFF_XB    ((size_t)16777216)   // 8192*512  bf16 =  8,388,608
#define OFF_H1    ((size_t)25165824)   // 8192*1024 bf16 = 16,777,216
#define OFF_XN    ((size_t)41943040)   // 8192*512  bf16 =  8,388,608
#define OFF_HEADB ((size_t)50331648)   // 32000*512 bf16 = 32,768,000
#define OFF_W1B   ((size_t)83099648)   // 1024*1536 bf16 =  3,145,728
#define OFF_W2B   ((size_t)86245376)   // 512*1024  bf16 =  1,048,576
#define OFF_EW1   ((size_t)87293952)   // 64*512    bf16 =     65,536
#define OFF_ENT   ((size_t)87359488)   // 8192 f32
#define OFF_CW    ((size_t)87392256)   // 8192 f32
#define OFF_HC    ((size_t)87425024)   // 1024 f32
#define OFF_B1    ((size_t)87431168)   // 1024 f32

__device__ __forceinline__ float gelu_f(float v) {
    return 0.5f * v * (1.0f + erff(v * 0.7071067811865475f));
}

__device__ __forceinline__ void load_lds16(const bf16_t* g, bf16_t* l) {
    __builtin_amdgcn_global_load_lds(
        (const __attribute__((address_space(1))) void*)g,
        (__attribute__((address_space(3))) void*)l, 16, 0, 0);
}

#define BAR()    __builtin_amdgcn_s_barrier()
#define SCHED0() __builtin_amdgcn_sched_barrier(0)
#define LGKM0()  asm volatile("s_waitcnt lgkmcnt(0)" ::: "memory")
#define WAITV0() asm volatile("s_waitcnt vmcnt(0)" ::: "memory")
#define WAITV2() asm volatile("s_waitcnt vmcnt(2)" ::: "memory")
#define WAITV4() asm volatile("s_waitcnt vmcnt(4)" ::: "memory")

// ---------------- f32 -> bf16 convert helper ----------------
__device__ __forceinline__ void cvt_store(const float4 v, __hip_bfloat162* dst) {
    __hip_bfloat162 p0, p1;
    p0.x = __float2bfloat16(v.x); p0.y = __float2bfloat16(v.y);
    p1.x = __float2bfloat16(v.z); p1.y = __float2bfloat16(v.w);
    dst[0] = p0; dst[1] = p1;
}

__device__ __forceinline__ void cvt_store_v(const f32x4_t v, __hip_bfloat162* dst) {
    __hip_bfloat162 p0, p1;
    p0.x = __float2bfloat16(v.x); p0.y = __float2bfloat16(v.y);
    p1.x = __float2bfloat16(v.z); p1.y = __float2bfloat16(v.w);
    dst[0] = p0; dst[1] = p1;
}

// ======= fused prologue A: [cvt3 (2080) | embed (4096) | prep1 (4)] = 6180 blocks =======
__global__ void pro_a_kernel(const float* __restrict__ cn_w1, const float* __restrict__ cn_w2,
                             const float* __restrict__ ent_w1,
                             bf16_t* __restrict__ w1b, bf16_t* __restrict__ w2b,
                             bf16_t* __restrict__ ew1b,
                             const int* __restrict__ tokens, const float* __restrict__ ew,
                             const float* __restrict__ pw, float* __restrict__ x,
                             bf16_t* __restrict__ xb,
                             const float* __restrict__ cs, const float* __restrict__ ctc_w1,
                             const float* __restrict__ ctc_b1, float* __restrict__ hc) {
    int bid = blockIdx.x;
    if (bid < 1536) {            // w1b: 1024 rows x first 1536 cols of cn_w1 (ld 2048)
        int idx = bid * 256 + threadIdx.x;
        int k4 = idx % 384;
        int o = idx / 384;
        float4 v = ((const float4*)(cn_w1 + (size_t)o * 2048))[k4];
        cvt_store(v, (__hip_bfloat162*)w1b + idx * 2);
    } else if (bid < 2048) {     // w2b: 512*1024 dense
        int idx = (bid - 1536) * 256 + threadIdx.x;
        float4 v = ((const float4*)cn_w2)[idx];
        cvt_store(v, (__hip_bfloat162*)w2b + idx * 2);
    } else if (bid < 2080) {     // ew1b: 64*512 dense
        int idx = (bid - 2048) * 256 + threadIdx.x;
        float4 v = ((const float4*)ent_w1)[idx];
        cvt_store(v, (__hip_bfloat162*)ew1b + idx * 2);
    } else if (bid < 6176) {     // embed: 8192*128 quads
        int idx = (bid - 2080) * 256 + threadIdx.x;
        int d4 = idx & 127;
        int bt = idx >> 7;
        int t = bt & 1023;
        int tok = tokens[bt];
        float4 e = ((const float4*)(ew + (size_t)tok * 512))[d4];
        float4 p = ((const float4*)(pw + (size_t)t * 512))[d4];
        float4 o = make_float4(e.x + p.x, e.y + p.y, e.z + p.z, e.w + p.w);
        ((float4*)x)[idx] = o;
        __hip_bfloat162 p0, p1;
        p0.x = __float2bfloat16(o.x); p0.y = __float2bfloat16(o.y);
        p1.x = __float2bfloat16(o.z); p1.y = __float2bfloat16(o.w);
        ((__hip_bfloat162*)xb)[idx * 2]     = p0;
        ((__hip_bfloat162*)xb)[idx * 2 + 1] = p1;
    } else {                     // prep1: 1024 outputs
        int o = (bid - 6176) * 256 + threadIdx.x;
        const float* wr = ctc_w1 + (size_t)o * 512;
        float acc = 0.f;
        for (int k = 0; k < 512; k += 4) {
            float4 w4 = *(const float4*)(wr + k);
            float4 a = *(const float4*)(cs + k);
            float4 b = *(const float4*)(cs + 512 + k);
            float4 c = *(const float4*)(cs + 1024 + k);
            float4 d = *(const float4*)(cs + 1536 + k);
            acc += w4.x * (a.x + b.x + c.x + d.x) * 0.25f;
            acc += w4.y * (a.y + b.y + c.y + d.y) * 0.25f;
            acc += w4.z * (a.z + b.z + c.z + d.z) * 0.25f;
            acc += w4.w * (a.w + b.w + c.w + d.w) * 0.25f;
        }
        hc[o] = gelu_f(acc + ctc_b1[o]);
    }
}

// ======= prep2+prep3 merged: one block, 1024 threads =======
__global__ __launch_bounds__(1024) void prep23_kernel(
        const float* __restrict__ hc, const float* __restrict__ ctc_w2,
        const float* __restrict__ ctc_b2, const float* __restrict__ cn_w1,
        const float* __restrict__ cn_b1, float* __restrict__ bias1) {
    __shared__ float cc_s[512];
    int o = threadIdx.x;
    if (o < 512) {
        const float* wr = ctc_w2 + (size_t)o * 1024;
        float acc = 0.f;
        for (int k = 0; k < 1024; ++k) acc += wr[k] * hc[k];
        cc_s[o] = acc + ctc_b2[o];
    }
    __syncthreads();
    const float* wr = cn_w1 + (size_t)o * 2048 + 1536;
    float acc = 0.f;
    for (int k = 0; k < 512; ++k) acc += wr[k] * cc_s[k];
    bias1[o] = acc + cn_b1[o];
}

// ---------------- entropy MLP via MFMA: 16 tokens per wave (R4 exact) ----------------
__global__ __launch_bounds__(256) void entropy_mfma(
        const bf16_t* __restrict__ xb, const bf16_t* __restrict__ w1b,
        const float* __restrict__ b1, const float* __restrict__ w2,
        const float* __restrict__ b2, float* __restrict__ ent) {
    int wave = threadIdx.x >> 6, lane = threadIdx.x & 63;
    int lr = lane & 15, kq = lane >> 4;
    int tok0 = (blockIdx.x * 4 + wave) * 16;
    f32x4_t acc[4] = {};
    const bf16_t* xr = xb + (size_t)(tok0 + lr) * 512 + kq * 8;
    const bf16_t* wr = w1b + (size_t)lr * 512 + kq * 8;
    #pragma unroll 4
    for (int k0 = 0; k0 < 512; k0 += 32) {
        bf16x8_t a = *(const bf16x8_t*)(xr + k0);
        #pragma unroll
        for (int j = 0; j < 4; ++j) {
            bf16x8_t bb = *(const bf16x8_t*)(wr + (size_t)j * 16 * 512 + k0);
            acc[j] = __builtin_amdgcn_mfma_f32_16x16x32_bf16(a, bb, acc[j], 0, 0, 0);
        }
    }
    float p[4];
    #pragma unroll
    for (int r = 0; r < 4; ++r) {
        float s = 0.f;
        #pragma unroll
        for (int j = 0; j < 4; ++j) {
            int n = j * 16 + lr;
            s += gelu_f(acc[j][r] + b1[n]) * w2[n];
        }
        #pragma unroll
        for (int o = 1; o < 16; o <<= 1) s += __shfl_xor(s, o);
        p[r] = s;
    }
    if (lr == 0) {
        float bb = b2[0];
        #pragma unroll
        for (int r = 0; r < 4; ++r) ent[tok0 + kq * 4 + r] = p[r] + bb;
    }
}

// ======= fused epilogue: [cvt headb (16000) | ln (2048)] = 18048 blocks =======
// head_w is a read-once 65.5 MB stream: nontemporal loads keep headb/xn L3-resident
// for the head GEMM that follows.
__global__ void epi_kernel(const float* __restrict__ head_w, bf16_t* __restrict__ headb,
                           const float* __restrict__ x, const float* __restrict__ g,
                           const float* __restrict__ b, bf16_t* __restrict__ xn) {
    int bid = blockIdx.x;
    if (bid < 16000) {           // headb convert: 32000*512/4 quads
        int idx = bid * 256 + threadIdx.x;
        f32x4_t v = __builtin_nontemporal_load((const f32x4_t*)head_w + idx);
        cvt_store_v(v, (__hip_bfloat162*)headb + idx * 2);
        return;
    }
    // LayerNorm: one wave per token
    int token = (bid - 16000) * 4 + (threadIdx.x >> 6);
    int l = threadIdx.x & 63;
    const float* xr = x + (size_t)token * 512;
    float4 v0 = ((const float4*)xr)[l * 2];
    float4 v1 = ((const float4*)xr)[l * 2 + 1];
    float s = v0.x + v0.y + v0.z + v0.w + v1.x + v1.y + v1.z + v1.w;
    float ss = v0.x * v0.x + v0.y * v0.y + v0.z * v0.z + v0.w * v0.w
             + v1.x * v1.x + v1.y * v1.y + v1.z * v1.z + v1.w * v1.w;
    #pragma unroll
    for (int o = 32; o; o >>= 1) { s += __shfl_xor(s, o); ss += __shfl_xor(ss, o); }
    float mu = s * (1.0f / 512.0f);
    float var = ss * (1.0f / 512.0f) - mu * mu;
    float rs = rsqrtf(var + 1e-5f);
    float4 g0 = ((const float4*)g)[l * 2], g1 = ((const float4*)g)[l * 2 + 1];
    float4 b0 = ((const float4*)b)[l * 2], b1 = ((const float4*)b)[l * 2 + 1];
    bf16_t* op = xn + (size_t)token * 512 + l * 8;
    op[0] = __float2bfloat16((v0.x - mu) * rs * g0.x + b0.x);
    op[1] = __float2bfloat16((v0.y - mu) * rs * g0.y + b0.y);
    op[2] = __float2bfloat16((v0.z - mu) * rs * g0.z + b0.z);
    op[3] = __float2bfloat16((v0.w - mu) * rs * g0.w + b0.w);
    op[4] = __float2bfloat16((v1.x - mu) * rs * g1.x + b1.x);
    op[5] = __float2bfloat16((v1.y - mu) * rs * g1.y + b1.y);
    op[6] = __float2bfloat16((v1.z - mu) * rs * g1.z + b1.z);
    op[7] = __float2bfloat16((v1.w - mu) * rs * g1.w + b1.w);
}

// ================= 8-phase 256xBN bf16 MFMA GEMM (R4-exact; MODE2 nt-stores) =======
// FUSE_SM: blocks [0,8) run the per-batch softmax (R11 refcheck'd variant).
template <int MODE, int ROLL, int BN, int FUSE_SM>
__global__ __launch_bounds__(512, 2) void gemm8p(
    const bf16_t* __restrict__ A, int lda,
    const bf16_t* __restrict__ B, int ldb, int K, int NMT, int ngemm,
    const float* __restrict__ bias,
    bf16_t* __restrict__ out_bf, int ldc,
    const float* __restrict__ cw, float* __restrict__ x,
    float* __restrict__ out_f,
    const float* __restrict__ entp, const float* __restrict__ btp,
    float stepf, float* __restrict__ cwout)
{
    constexpr int JJ = BN / 64;                 // B-frags per wave per kk (4 or 2)
    __shared__ __align__(16) bf16_t As[2][256 * 64];
    __shared__ __align__(16) bf16_t Bs[2][BN * 64];
    __shared__ float sred[8];
    __shared__ float sbc[2];

    const int tid = threadIdx.x;
    const int wave = tid >> 6, lane = tid & 63;

    if (FUSE_SM && (int)blockIdx.x < 8) {
        const float* eb = entp + (size_t)blockIdx.x * 1024;
        float bt = btp[0];
        float sp = (bt > 20.0f) ? bt : log1pf(expf(bt));
        float inv = -1.0f / (sp * stepf);
        float v0 = eb[tid] * inv;
        float v1 = eb[tid + 512] * inv;
        float mx = fmaxf(v0, v1);
        #pragma unroll
        for (int o = 32; o; o >>= 1) mx = fmaxf(mx, __shfl_xor(mx, o));
        if (lane == 0) sred[wave] = mx;
        __syncthreads();
        if (tid < 64) {
            float mm = (tid < 8) ? sred[tid] : -3.4e38f;
            #pragma unroll
            for (int o = 4; o; o >>= 1) mm = fmaxf(mm, __shfl_xor(mm, o));
            if (tid == 0) sbc[0] = mm;
        }
        __syncthreads();
        float M = sbc[0];
        float e0 = expf(v0 - M), e1 = expf(v1 - M);
        float s = e0 + e1;
        #pragma unroll
        for (int o = 32; o; o >>= 1) s += __shfl_xor(s, o);
        if (lane == 0) sred[wave] = s;
        __syncthreads();
        if (tid < 64) {
            float ssum = (tid < 8) ? sred[tid] : 0.f;
            #pragma unroll
            for (int o = 4; o; o >>= 1) ssum += __shfl_xor(ssum, o);
            if (tid == 0) sbc[1] = ssum;
        }
        __syncthreads();
        float S = sbc[1];
        cwout[blockIdx.x * 1024 + tid]       = e0 / S;
        cwout[blockIdx.x * 1024 + tid + 512] = e1 / S;
        return;
    }

    const int NT = K >> 6;
    const int id0 = (int)blockIdx.x - (FUSE_SM ? 8 : 0);
    const int id = (id0 & 7) * (ngemm >> 3) + (id0 >> 3);  // bijective XCD swizzle (ngemm%8==0)
    const int m0 = (id % NMT) * 256;
    const int n0 = (id / NMT) * BN;

    const int wm = (wave >> 2) * 128;
    const int wn = (wave & 3) * (BN / 4);
    const int lr = lane & 15, kq = lane >> 4;

    const int swz0 = (kq)     ^ (lr & 7);
    const int swz1 = (4 + kq) ^ (lr & 7);
    const int eoff0 = lr * 64 + swz0 * 8;
    const int eoff1 = lr * 64 + swz1 * 8;

    const int u0row = tid >> 3;                 // 0..63
    const int u1row = 64 + (tid >> 3);          // 64..127
    const int usl   = tid & 7;
    const int c0 = ((usl ^ (u0row & 7)) * 8);
    const int c1 = ((usl ^ (u1row & 7)) * 8);

    f32x4_t acc[8][JJ] = {};
    bf16x8_t bfr[JJ][2];

    auto stageA = [&](int ktile, int c, int half) {
        const int kbase = ktile << 6;
        const int r0 = m0 + half * 128 + u0row;
        const int r1 = m0 + half * 128 + u1row;
        const bf16_t *g0, *g1;
        if (ROLL) {
            const int seg = kbase >> 9;
            const int kk2 = kbase & 511;
            const int sh = (seg == 0) ? 0 : ((seg == 1) ? 1023 : 1);
            const int s0 = (r0 & ~1023) | (((r0 & 1023) + sh) & 1023);
            const int s1 = (r1 & ~1023) | (((r1 & 1023) + sh) & 1023);
            g0 = A + (size_t)s0 * 512 + kk2 + c0;
            g1 = A + (size_t)s1 * 512 + kk2 + c1;
        } else {
            g0 = A + (size_t)r0 * lda + kbase + c0;
            g1 = A + (size_t)r1 * lda + kbase + c1;
        }
        bf16_t* l = &As[c][half * 128 * 64];
        load_lds16(g0, l + tid * 8);
        load_lds16(g1, l + (tid + 512) * 8);
    };
    auto stageB = [&](int ktile, int c, int half) {
        const int kbase = ktile << 6;
        const int r0 = n0 + half * 128 + u0row;
        const int r1 = n0 + half * 128 + u1row;
        const bf16_t* g0 = B + (size_t)r0 * ldb + kbase + c0;
        const bf16_t* g1 = B + (size_t)r1 * ldb + kbase + c1;
        bf16_t* l = &Bs[c][half * 128 * 64];
        load_lds16(g0, l + tid * 8);
        load_lds16(g1, l + (tid + 512) * 8);
    };

    // ---- prologue: A(0), B(0) resident; B(1) in flight ----
    stageA(0, 0, 0); stageA(0, 0, 1);
    stageB(0, 0, 0); if (BN == 256) stageB(0, 0, 1);
    stageB(1, 1, 0); if (BN == 256) stageB(1, 1, 1);
    if (BN == 256) { WAITV4(); } else { WAITV2(); }
    BAR();

    int cur = 0;
    for (int t = 0; t < NT; ++t) {
        #pragma unroll
        for (int p = 0; p < 4; ++p) {
            bf16x8_t af0k0, af0k1, af1k0, af1k1;
            {
                const int r0 = (wm + 32 * p + lr) * 64;
                const int r1 = (wm + 32 * p + 16 + lr) * 64;
                af0k0 = *(const bf16x8_t*)&As[cur][r0 - lr * 64 + eoff0];
                af0k1 = *(const bf16x8_t*)&As[cur][r0 - lr * 64 + eoff1];
                af1k0 = *(const bf16x8_t*)&As[cur][r1 - lr * 64 + eoff0];
                af1k1 = *(const bf16x8_t*)&As[cur][r1 - lr * 64 + eoff1];
            }
            if (p == 0) {
                #pragma unroll
                for (int j = 0; j < JJ; ++j) {
                    const int rb = (wn + 16 * j) * 64;
                    bfr[j][0] = *(const bf16x8_t*)&Bs[cur][rb + eoff0];
                    bfr[j][1] = *(const bf16x8_t*)&Bs[cur][rb + eoff1];
                }
            }
            if (p == 0 && t + 1 < NT) stageA(t + 1, cur ^ 1, 0);
            if (p == 1 && t + 1 < NT) stageA(t + 1, cur ^ 1, 1);
            if (p == 2 && t + 2 < NT) stageB(t + 2, cur, 0);
            if (p == 3 && BN == 256 && t + 2 < NT) stageB(t + 2, cur, 1);

            BAR();
            LGKM0();
            SCHED0();
            __builtin_amdgcn_s_setprio(1);
            #pragma unroll
            for (int j = 0; j < JJ; ++j) {
                acc[2*p][j]   = __builtin_amdgcn_mfma_f32_16x16x32_bf16(af0k0, bfr[j][0], acc[2*p][j],   0, 0, 0);
                acc[2*p+1][j] = __builtin_amdgcn_mfma_f32_16x16x32_bf16(af1k0, bfr[j][0], acc[2*p+1][j], 0, 0, 0);
            }
            #pragma unroll
            for (int j = 0; j < JJ; ++j) {
                acc[2*p][j]   = __builtin_amdgcn_mfma_f32_16x16x32_bf16(af0k1, bfr[j][1], acc[2*p][j],   0, 0, 0);
                acc[2*p+1][j] = __builtin_amdgcn_mfma_f32_16x16x32_bf16(af1k1, bfr[j][1], acc[2*p+1][j], 0, 0, 0);
            }
            __builtin_amdgcn_s_setprio(0);
            SCHED0();
            if (p == 3) {
                if (t + 2 < NT) { if (BN == 256) { WAITV4(); } else { WAITV2(); } }
                else           { WAITV0(); }
            }
            BAR();
        }
        cur ^= 1;
    }

    // ---- epilogue ----
    #pragma unroll
    for (int i = 0; i < 8; ++i) {
        const int rbase = m0 + wm + i * 16 + kq * 4;   // C/D: row=(lane>>4)*4+reg
        #pragma unroll
        for (int j = 0; j < JJ; ++j) {
            const int gcol = n0 + wn + j * 16 + lr;    // C/D: col=lane&15
            #pragma unroll
            for (int r = 0; r < 4; ++r) {
                const size_t grow = (size_t)(rbase + r);
                float v = acc[i][j][r];
                if (MODE == 0) {
                    v = gelu_f(v + bias[gcol]);
                    out_bf[grow * ldc + gcol] = __float2bfloat16(v);
                } else if (MODE == 1) {
                    v += bias[gcol];
                    float nv = x[grow * ldc + gcol] + v * cw[grow] * 0.3f;
                    x[grow * ldc + gcol] = nv;
                    out_bf[grow * ldc + gcol] = __float2bfloat16(nv);
                } else {
                    // write-once 1.05 GB stream: bypass caches (R10: -79 us)
                    __builtin_nontemporal_store(v, &out_f[grow * ldc + gcol]);
                }
            }
        }
    }
}

extern "C" void kernel_launch(void* const* d_in, const int* in_sizes, int n_in,
                              void* d_out, int out_size, void* d_ws, size_t ws_size,
                              hipStream_t stream) {
    const int*   tokens   = (const int*)d_in[0];
    const float* c_states = (const float*)d_in[1];
    const float* embed_w  = (const float*)d_in[2];
    const float* pos_w    = (const float*)d_in[3];
    const float* cn_w1    = (const float*)d_in[4];
    const float* cn_b1    = (const float*)d_in[5];
    const float* cn_w2    = (const float*)d_in[6];
    const float* cn_b2    = (const float*)d_in[7];
    const float* ent_w1   = (const float*)d_in[8];
    const float* ent_b1   = (const float*)d_in[9];
    const float* ent_w2   = (const float*)d_in[10];
    const float* ent_b2   = (const float*)d_in[11];
    const float* ctc_w1   = (const float*)d_in[12];
    const float* ctc_b1   = (const float*)d_in[13];
    const float* ctc_w2   = (const float*)d_in[14];
    const float* ctc_b2   = (const float*)d_in[15];
    const float* base_temp= (const float*)d_in[16];
    const float* ln_g     = (const float*)d_in[17];
    const float* ln_b     = (const float*)d_in[18];
    const float* head_w   = (const float*)d_in[19];
    float* out = (float*)d_out;

    char* ws = (char*)d_ws;
    float*  x     = (float*)(ws + OFF_X);
    bf16_t* xb    = (bf16_t*)(ws + OFF_XB);
    bf16_t* h1    = (bf16_t*)(ws + OFF_H1);
    bf16_t* xn    = (bf16_t*)(ws + OFF_XN);
    bf16_t* headb = (bf16_t*)(ws + OFF_HEADB);
    bf16_t* w1b   = (bf16_t*)(ws + OFF_W1B);
    bf16_t* w2b   = (bf16_t*)(ws + OFF_W2B);
    bf16_t* ew1b  = (bf16_t*)(ws + OFF_EW1);
    float*  ent   = (float*)(ws + OFF_ENT);
    float*  cw    = (float*)(ws + OFF_CW);
    float*  hc    = (float*)(ws + OFF_HC);
    float*  bias1 = (float*)(ws + OFF_B1);

    // fused prologue: [cvt3 | embed | prep1]; then merged prep2+prep3
    pro_a_kernel<<<6180, 256, 0, stream>>>(cn_w1, cn_w2, ent_w1, w1b, w2b, ew1b,
                                           tokens, embed_w, pos_w, x, xb,
                                           c_states, ctc_w1, ctc_b1, hc);
    prep23_kernel<<<1, 1024, 0, stream>>>(hc, ctc_w2, ctc_b2, cn_w1, cn_b1, bias1);

    for (int step = 0; step < 6; ++step) {
        float stepf = 1.0f - ((float)step / 6.0f) * 0.8f;
        entropy_mfma<<<128, 256, 0, stream>>>(xb, ew1b, ent_b1, ent_w2, ent_b2, ent);
        // gemm1 + fused softmax (8 leading blocks): 8 + 256 = 264 blocks (R11 config)
        gemm8p<0, 1, 128, 1><<<264, 512, 0, stream>>>(
            xb, 512, w1b, 1536, 1536, 32, 256,
            bias1, h1, 1024, nullptr, nullptr, nullptr,
            ent, base_temp, stepf, cw);
        // gemm2: [8192x1024]x[512x1024]^T, 256x128 tiles -> 128 blocks
        gemm8p<1, 0, 128, 0><<<128, 512, 0, stream>>>(
            h1, 1024, w2b, 1024, 1024, 32, 128,
            cn_b2, xb, 512, cw, x, nullptr,
            nullptr, nullptr, 0.f, nullptr);
    }

    // fused epilogue: [cvt headb (nt-load) | ln]
    epi_kernel<<<18048, 256, 0, stream>>>(head_w, headb, x, ln_g, ln_b, xn);
    // head: [8192x512]x[32000x512]^T, 256x256 tiles -> 4000 blocks
    gemm8p<2, 0, 256, 0><<<4000, 512, 0, stream>>>(
        xn, 512, headb, 512, 512, 32, 4000,
        nullptr, nullptr, 32000, nullptr, nullptr, out,
        nullptr, nullptr, 0.f, nullptr);
}

// Round 15
// 1197.682 us; speedup vs baseline: 1.0646x; 1.0031x over previous
//
#include <hip/hip_runtime.h>
#include <hip/hip_bf16.h>

typedef __hip_bfloat16 bf16_t;
typedef __bf16 bf16x8_t __attribute__((ext_vector_type(8)));
typedef float f32x4_t __attribute__((ext_vector_type(4)));

// ---------------- workspace layout (bytes) ----------------
#define OFF_X     ((size_t)0)          // 8192*512  f32  = 16,777,216
#define OFF_XB    ((size_t)16777216)   // 8192*512  bf16 =  8,388,608
#define OFF_H1    ((size_t)25165824)   // 8192*1024 bf16 = 16,777,216
#define OFF_XN    ((size_t)41943040)   // 8192*512  bf16 =  8,388,608
#define OFF_HEADB ((size_t)50331648)   // 32000*512 bf16 = 32,768,000
#define OFF_W1B   ((size_t)83099648)   // 1024*1536 bf16 =  3,145,728
#define OFF_W2B   ((size_t)86245376)   // 512*1024  bf16 =  1,048,576
#define OFF_EW1   ((size_t)87293952)   // 64*512    bf16 =     65,536
#define OFF_ENT   ((size_t)87359488)   // 8192 f32
#define OFF_CW    ((size_t)87392256)   // 8192 f32
#define OFF_HC    ((size_t)87425024)   // 1024 f32
#define OFF_B1    ((size_t)87431168)   // 1024 f32

__device__ __forceinline__ float gelu_f(float v) {
    return 0.5f * v * (1.0f + erff(v * 0.7071067811865475f));
}

__device__ __forceinline__ void load_lds16(const bf16_t* g, bf16_t* l) {
    __builtin_amdgcn_global_load_lds(
        (const __attribute__((address_space(1))) void*)g,
        (__attribute__((address_space(3))) void*)l, 16, 0, 0);
}

#define BAR()    __builtin_amdgcn_s_barrier()
#define SCHED0() __builtin_amdgcn_sched_barrier(0)
#define LGKM0()  asm volatile("s_waitcnt lgkmcnt(0)" ::: "memory")
#define WAITV0() asm volatile("s_waitcnt vmcnt(0)" ::: "memory")
#define WAITV2() asm volatile("s_waitcnt vmcnt(2)" ::: "memory")
#define WAITV4() asm volatile("s_waitcnt vmcnt(4)" ::: "memory")

// ---------------- f32 -> bf16 convert helper ----------------
__device__ __forceinline__ void cvt_store(const float4 v, __hip_bfloat162* dst) {
    __hip_bfloat162 p0, p1;
    p0.x = __float2bfloat16(v.x); p0.y = __float2bfloat16(v.y);
    p1.x = __float2bfloat16(v.z); p1.y = __float2bfloat16(v.w);
    dst[0] = p0; dst[1] = p1;
}

// ======= fused prologue A: [cvt3 (2080) | embed (4096) | prep1 (4)] = 6180 blocks =======
__global__ void pro_a_kernel(const float* __restrict__ cn_w1, const float* __restrict__ cn_w2,
                             const float* __restrict__ ent_w1,
                             bf16_t* __restrict__ w1b, bf16_t* __restrict__ w2b,
                             bf16_t* __restrict__ ew1b,
                             const int* __restrict__ tokens, const float* __restrict__ ew,
                             const float* __restrict__ pw, float* __restrict__ x,
                             bf16_t* __restrict__ xb,
                             const float* __restrict__ cs, const float* __restrict__ ctc_w1,
                             const float* __restrict__ ctc_b1, float* __restrict__ hc) {
    int bid = blockIdx.x;
    if (bid < 1536) {            // w1b: 1024 rows x first 1536 cols of cn_w1 (ld 2048)
        int idx = bid * 256 + threadIdx.x;
        int k4 = idx % 384;
        int o = idx / 384;
        float4 v = ((const float4*)(cn_w1 + (size_t)o * 2048))[k4];
        cvt_store(v, (__hip_bfloat162*)w1b + idx * 2);
    } else if (bid < 2048) {     // w2b: 512*1024 dense
        int idx = (bid - 1536) * 256 + threadIdx.x;
        float4 v = ((const float4*)cn_w2)[idx];
        cvt_store(v, (__hip_bfloat162*)w2b + idx * 2);
    } else if (bid < 2080) {     // ew1b: 64*512 dense
        int idx = (bid - 2048) * 256 + threadIdx.x;
        float4 v = ((const float4*)ent_w1)[idx];
        cvt_store(v, (__hip_bfloat162*)ew1b + idx * 2);
    } else if (bid < 6176) {     // embed: 8192*128 quads
        int idx = (bid - 2080) * 256 + threadIdx.x;
        int d4 = idx & 127;
        int bt = idx >> 7;
        int t = bt & 1023;
        int tok = tokens[bt];
        float4 e = ((const float4*)(ew + (size_t)tok * 512))[d4];
        float4 p = ((const float4*)(pw + (size_t)t * 512))[d4];
        float4 o = make_float4(e.x + p.x, e.y + p.y, e.z + p.z, e.w + p.w);
        ((float4*)x)[idx] = o;
        __hip_bfloat162 p0, p1;
        p0.x = __float2bfloat16(o.x); p0.y = __float2bfloat16(o.y);
        p1.x = __float2bfloat16(o.z); p1.y = __float2bfloat16(o.w);
        ((__hip_bfloat162*)xb)[idx * 2]     = p0;
        ((__hip_bfloat162*)xb)[idx * 2 + 1] = p1;
    } else {                     // prep1: 1024 outputs
        int o = (bid - 6176) * 256 + threadIdx.x;
        const float* wr = ctc_w1 + (size_t)o * 512;
        float acc = 0.f;
        for (int k = 0; k < 512; k += 4) {
            float4 w4 = *(const float4*)(wr + k);
            float4 a = *(const float4*)(cs + k);
            float4 b = *(const float4*)(cs + 512 + k);
            float4 c = *(const float4*)(cs + 1024 + k);
            float4 d = *(const float4*)(cs + 1536 + k);
            acc += w4.x * (a.x + b.x + c.x + d.x) * 0.25f;
            acc += w4.y * (a.y + b.y + c.y + d.y) * 0.25f;
            acc += w4.z * (a.z + b.z + c.z + d.z) * 0.25f;
            acc += w4.w * (a.w + b.w + c.w + d.w) * 0.25f;
        }
        hc[o] = gelu_f(acc + ctc_b1[o]);
    }
}

// ======= prep2+prep3 merged: one block, 1024 threads =======
__global__ __launch_bounds__(1024) void prep23_kernel(
        const float* __restrict__ hc, const float* __restrict__ ctc_w2,
        const float* __restrict__ ctc_b2, const float* __restrict__ cn_w1,
        const float* __restrict__ cn_b1, float* __restrict__ bias1) {
    __shared__ float cc_s[512];
    int o = threadIdx.x;
    if (o < 512) {
        const float* wr = ctc_w2 + (size_t)o * 1024;
        float acc = 0.f;
        for (int k = 0; k < 1024; ++k) acc += wr[k] * hc[k];
        cc_s[o] = acc + ctc_b2[o];
    }
    __syncthreads();
    const float* wr = cn_w1 + (size_t)o * 2048 + 1536;
    float acc = 0.f;
    for (int k = 0; k < 512; ++k) acc += wr[k] * cc_s[k];
    bias1[o] = acc + cn_b1[o];
}

// ---------------- entropy MLP via MFMA: 16 tokens per wave (R4 exact) ----------------
__global__ __launch_bounds__(256) void entropy_mfma(
        const bf16_t* __restrict__ xb, const bf16_t* __restrict__ w1b,
        const float* __restrict__ b1, const float* __restrict__ w2,
        const float* __restrict__ b2, float* __restrict__ ent) {
    int wave = threadIdx.x >> 6, lane = threadIdx.x & 63;
    int lr = lane & 15, kq = lane >> 4;
    int tok0 = (blockIdx.x * 4 + wave) * 16;
    f32x4_t acc[4] = {};
    const bf16_t* xr = xb + (size_t)(tok0 + lr) * 512 + kq * 8;
    const bf16_t* wr = w1b + (size_t)lr * 512 + kq * 8;
    #pragma unroll 4
    for (int k0 = 0; k0 < 512; k0 += 32) {
        bf16x8_t a = *(const bf16x8_t*)(xr + k0);
        #pragma unroll
        for (int j = 0; j < 4; ++j) {
            bf16x8_t bb = *(const bf16x8_t*)(wr + (size_t)j * 16 * 512 + k0);
            acc[j] = __builtin_amdgcn_mfma_f32_16x16x32_bf16(a, bb, acc[j], 0, 0, 0);
        }
    }
    float p[4];
    #pragma unroll
    for (int r = 0; r < 4; ++r) {
        float s = 0.f;
        #pragma unroll
        for (int j = 0; j < 4; ++j) {
            int n = j * 16 + lr;
            s += gelu_f(acc[j][r] + b1[n]) * w2[n];
        }
        #pragma unroll
        for (int o = 1; o < 16; o <<= 1) s += __shfl_xor(s, o);
        p[r] = s;
    }
    if (lr == 0) {
        float bb = b2[0];
        #pragma unroll
        for (int r = 0; r < 4; ++r) ent[tok0 + kq * 4 + r] = p[r] + bb;
    }
}

// ======= fused epilogue: [cvt headb (16000) | ln (2048)] = 18048 blocks =======
__global__ void epi_kernel(const float* __restrict__ head_w, bf16_t* __restrict__ headb,
                           const float* __restrict__ x, const float* __restrict__ g,
                           const float* __restrict__ b, bf16_t* __restrict__ xn) {
    int bid = blockIdx.x;
    if (bid < 16000) {           // headb convert: 32000*512/4 quads (plain loads — R14: nt-load hurt)
        int idx = bid * 256 + threadIdx.x;
        float4 v = ((const float4*)head_w)[idx];
        cvt_store(v, (__hip_bfloat162*)headb + idx * 2);
        return;
    }
    // LayerNorm: one wave per token
    int token = (bid - 16000) * 4 + (threadIdx.x >> 6);
    int l = threadIdx.x & 63;
    const float* xr = x + (size_t)token * 512;
    float4 v0 = ((const float4*)xr)[l * 2];
    float4 v1 = ((const float4*)xr)[l * 2 + 1];
    float s = v0.x + v0.y + v0.z + v0.w + v1.x + v1.y + v1.z + v1.w;
    float ss = v0.x * v0.x + v0.y * v0.y + v0.z * v0.z + v0.w * v0.w
             + v1.x * v1.x + v1.y * v1.y + v1.z * v1.z + v1.w * v1.w;
    #pragma unroll
    for (int o = 32; o; o >>= 1) { s += __shfl_xor(s, o); ss += __shfl_xor(ss, o); }
    float mu = s * (1.0f / 512.0f);
    float var = ss * (1.0f / 512.0f) - mu * mu;
    float rs = rsqrtf(var + 1e-5f);
    float4 g0 = ((const float4*)g)[l * 2], g1 = ((const float4*)g)[l * 2 + 1];
    float4 b0 = ((const float4*)b)[l * 2], b1 = ((const float4*)b)[l * 2 + 1];
    bf16_t* op = xn + (size_t)token * 512 + l * 8;
    op[0] = __float2bfloat16((v0.x - mu) * rs * g0.x + b0.x);
    op[1] = __float2bfloat16((v0.y - mu) * rs * g0.y + b0.y);
    op[2] = __float2bfloat16((v0.z - mu) * rs * g0.z + b0.z);
    op[3] = __float2bfloat16((v0.w - mu) * rs * g0.w + b0.w);
    op[4] = __float2bfloat16((v1.x - mu) * rs * g1.x + b1.x);
    op[5] = __float2bfloat16((v1.y - mu) * rs * g1.y + b1.y);
    op[6] = __float2bfloat16((v1.z - mu) * rs * g1.z + b1.z);
    op[7] = __float2bfloat16((v1.w - mu) * rs * g1.w + b1.w);
}

// ================= 8-phase 256xBN bf16 MFMA GEMM (R4-exact; MODE2 nt-stores) =======
// FUSE_SM: blocks [0,8) run the per-batch softmax (R11 refcheck'd variant).
template <int MODE, int ROLL, int BN, int FUSE_SM>
__global__ __launch_bounds__(512, 2) void gemm8p(
    const bf16_t* __restrict__ A, int lda,
    const bf16_t* __restrict__ B, int ldb, int K, int NMT, int ngemm,
    const float* __restrict__ bias,
    bf16_t* __restrict__ out_bf, int ldc,
    const float* __restrict__ cw, float* __restrict__ x,
    float* __restrict__ out_f,
    const float* __restrict__ entp, const float* __restrict__ btp,
    float stepf, float* __restrict__ cwout)
{
    constexpr int JJ = BN / 64;                 // B-frags per wave per kk (4 or 2)
    __shared__ __align__(16) bf16_t As[2][256 * 64];
    __shared__ __align__(16) bf16_t Bs[2][BN * 64];
    __shared__ float sred[8];
    __shared__ float sbc[2];

    const int tid = threadIdx.x;
    const int wave = tid >> 6, lane = tid & 63;

    if (FUSE_SM && (int)blockIdx.x < 8) {
        const float* eb = entp + (size_t)blockIdx.x * 1024;
        float bt = btp[0];
        float sp = (bt > 20.0f) ? bt : log1pf(expf(bt));
        float inv = -1.0f / (sp * stepf);
        float v0 = eb[tid] * inv;
        float v1 = eb[tid + 512] * inv;
        float mx = fmaxf(v0, v1);
        #pragma unroll
        for (int o = 32; o; o >>= 1) mx = fmaxf(mx, __shfl_xor(mx, o));
        if (lane == 0) sred[wave] = mx;
        __syncthreads();
        if (tid < 64) {
            float mm = (tid < 8) ? sred[tid] : -3.4e38f;
            #pragma unroll
            for (int o = 4; o; o >>= 1) mm = fmaxf(mm, __shfl_xor(mm, o));
            if (tid == 0) sbc[0] = mm;
        }
        __syncthreads();
        float M = sbc[0];
        float e0 = expf(v0 - M), e1 = expf(v1 - M);
        float s = e0 + e1;
        #pragma unroll
        for (int o = 32; o; o >>= 1) s += __shfl_xor(s, o);
        if (lane == 0) sred[wave] = s;
        __syncthreads();
        if (tid < 64) {
            float ssum = (tid < 8) ? sred[tid] : 0.f;
            #pragma unroll
            for (int o = 4; o; o >>= 1) ssum += __shfl_xor(ssum, o);
            if (tid == 0) sbc[1] = ssum;
        }
        __syncthreads();
        float S = sbc[1];
        cwout[blockIdx.x * 1024 + tid]       = e0 / S;
        cwout[blockIdx.x * 1024 + tid + 512] = e1 / S;
        return;
    }

    const int NT = K >> 6;
    const int id0 = (int)blockIdx.x - (FUSE_SM ? 8 : 0);
    const int id = (id0 & 7) * (ngemm >> 3) + (id0 >> 3);  // bijective XCD swizzle (ngemm%8==0)
    const int m0 = (id % NMT) * 256;
    const int n0 = (id / NMT) * BN;

    const int wm = (wave >> 2) * 128;
    const int wn = (wave & 3) * (BN / 4);
    const int lr = lane & 15, kq = lane >> 4;

    const int swz0 = (kq)     ^ (lr & 7);
    const int swz1 = (4 + kq) ^ (lr & 7);
    const int eoff0 = lr * 64 + swz0 * 8;
    const int eoff1 = lr * 64 + swz1 * 8;

    const int u0row = tid >> 3;                 // 0..63
    const int u1row = 64 + (tid >> 3);          // 64..127
    const int usl   = tid & 7;
    const int c0 = ((usl ^ (u0row & 7)) * 8);
    const int c1 = ((usl ^ (u1row & 7)) * 8);

    f32x4_t acc[8][JJ] = {};
    bf16x8_t bfr[JJ][2];

    auto stageA = [&](int ktile, int c, int half) {
        const int kbase = ktile << 6;
        const int r0 = m0 + half * 128 + u0row;
        const int r1 = m0 + half * 128 + u1row;
        const bf16_t *g0, *g1;
        if (ROLL) {
            const int seg = kbase >> 9;
            const int kk2 = kbase & 511;
            const int sh = (seg == 0) ? 0 : ((seg == 1) ? 1023 : 1);
            const int s0 = (r0 & ~1023) | (((r0 & 1023) + sh) & 1023);
            const int s1 = (r1 & ~1023) | (((r1 & 1023) + sh) & 1023);
            g0 = A + (size_t)s0 * 512 + kk2 + c0;
            g1 = A + (size_t)s1 * 512 + kk2 + c1;
        } else {
            g0 = A + (size_t)r0 * lda + kbase + c0;
            g1 = A + (size_t)r1 * lda + kbase + c1;
        }
        bf16_t* l = &As[c][half * 128 * 64];
        load_lds16(g0, l + tid * 8);
        load_lds16(g1, l + (tid + 512) * 8);
    };
    auto stageB = [&](int ktile, int c, int half) {
        const int kbase = ktile << 6;
        const int r0 = n0 + half * 128 + u0row;
        const int r1 = n0 + half * 128 + u1row;
        const bf16_t* g0 = B + (size_t)r0 * ldb + kbase + c0;
        const bf16_t* g1 = B + (size_t)r1 * ldb + kbase + c1;
        bf16_t* l = &Bs[c][half * 128 * 64];
        load_lds16(g0, l + tid * 8);
        load_lds16(g1, l + (tid + 512) * 8);
    };

    // ---- prologue: A(0), B(0) resident; B(1) in flight ----
    stageA(0, 0, 0); stageA(0, 0, 1);
    stageB(0, 0, 0); if (BN == 256) stageB(0, 0, 1);
    stageB(1, 1, 0); if (BN == 256) stageB(1, 1, 1);
    if (BN == 256) { WAITV4(); } else { WAITV2(); }
    BAR();

    int cur = 0;
    for (int t = 0; t < NT; ++t) {
        #pragma unroll
        for (int p = 0; p < 4; ++p) {
            bf16x8_t af0k0, af0k1, af1k0, af1k1;
            {
                const int r0 = (wm + 32 * p + lr) * 64;
                const int r1 = (wm + 32 * p + 16 + lr) * 64;
                af0k0 = *(const bf16x8_t*)&As[cur][r0 - lr * 64 + eoff0];
                af0k1 = *(const bf16x8_t*)&As[cur][r0 - lr * 64 + eoff1];
                af1k0 = *(const bf16x8_t*)&As[cur][r1 - lr * 64 + eoff0];
                af1k1 = *(const bf16x8_t*)&As[cur][r1 - lr * 64 + eoff1];
            }
            if (p == 0) {
                #pragma unroll
                for (int j = 0; j < JJ; ++j) {
                    const int rb = (wn + 16 * j) * 64;
                    bfr[j][0] = *(const bf16x8_t*)&Bs[cur][rb + eoff0];
                    bfr[j][1] = *(const bf16x8_t*)&Bs[cur][rb + eoff1];
                }
            }
            if (p == 0 && t + 1 < NT) stageA(t + 1, cur ^ 1, 0);
            if (p == 1 && t + 1 < NT) stageA(t + 1, cur ^ 1, 1);
            if (p == 2 && t + 2 < NT) stageB(t + 2, cur, 0);
            if (p == 3 && BN == 256 && t + 2 < NT) stageB(t + 2, cur, 1);

            BAR();
            LGKM0();
            SCHED0();
            __builtin_amdgcn_s_setprio(1);
            #pragma unroll
            for (int j = 0; j < JJ; ++j) {
                acc[2*p][j]   = __builtin_amdgcn_mfma_f32_16x16x32_bf16(af0k0, bfr[j][0], acc[2*p][j],   0, 0, 0);
                acc[2*p+1][j] = __builtin_amdgcn_mfma_f32_16x16x32_bf16(af1k0, bfr[j][0], acc[2*p+1][j], 0, 0, 0);
            }
            #pragma unroll
            for (int j = 0; j < JJ; ++j) {
                acc[2*p][j]   = __builtin_amdgcn_mfma_f32_16x16x32_bf16(af0k1, bfr[j][1], acc[2*p][j],   0, 0, 0);
                acc[2*p+1][j] = __builtin_amdgcn_mfma_f32_16x16x32_bf16(af1k1, bfr[j][1], acc[2*p+1][j], 0, 0, 0);
            }
            __builtin_amdgcn_s_setprio(0);
            SCHED0();
            if (p == 3) {
                if (t + 2 < NT) { if (BN == 256) { WAITV4(); } else { WAITV2(); } }
                else           { WAITV0(); }
            }
            BAR();
        }
        cur ^= 1;
    }

    // ---- epilogue ----
    #pragma unroll
    for (int i = 0; i < 8; ++i) {
        const int rbase = m0 + wm + i * 16 + kq * 4;   // C/D: row=(lane>>4)*4+reg
        #pragma unroll
        for (int j = 0; j < JJ; ++j) {
            const int gcol = n0 + wn + j * 16 + lr;    // C/D: col=lane&15
            #pragma unroll
            for (int r = 0; r < 4; ++r) {
                const size_t grow = (size_t)(rbase + r);
                float v = acc[i][j][r];
                if (MODE == 0) {
                    v = gelu_f(v + bias[gcol]);
                    out_bf[grow * ldc + gcol] = __float2bfloat16(v);
                } else if (MODE == 1) {
                    v += bias[gcol];
                    float nv = x[grow * ldc + gcol] + v * cw[grow] * 0.3f;
                    x[grow * ldc + gcol] = nv;
                    out_bf[grow * ldc + gcol] = __float2bfloat16(nv);
                } else {
                    // write-once 1.05 GB stream: bypass caches (R10: -79 us)
                    __builtin_nontemporal_store(v, &out_f[grow * ldc + gcol]);
                }
            }
        }
    }
}

extern "C" void kernel_launch(void* const* d_in, const int* in_sizes, int n_in,
                              void* d_out, int out_size, void* d_ws, size_t ws_size,
                              hipStream_t stream) {
    const int*   tokens   = (const int*)d_in[0];
    const float* c_states = (const float*)d_in[1];
    const float* embed_w  = (const float*)d_in[2];
    const float* pos_w    = (const float*)d_in[3];
    const float* cn_w1    = (const float*)d_in[4];
    const float* cn_b1    = (const float*)d_in[5];
    const float* cn_w2    = (const float*)d_in[6];
    const float* cn_b2    = (const float*)d_in[7];
    const float* ent_w1   = (const float*)d_in[8];
    const float* ent_b1   = (const float*)d_in[9];
    const float* ent_w2   = (const float*)d_in[10];
    const float* ent_b2   = (const float*)d_in[11];
    const float* ctc_w1   = (const float*)d_in[12];
    const float* ctc_b1   = (const float*)d_in[13];
    const float* ctc_w2   = (const float*)d_in[14];
    const float* ctc_b2   = (const float*)d_in[15];
    const float* base_temp= (const float*)d_in[16];
    const float* ln_g     = (const float*)d_in[17];
    const float* ln_b     = (const float*)d_in[18];
    const float* head_w   = (const float*)d_in[19];
    float* out = (float*)d_out;

    char* ws = (char*)d_ws;
    float*  x     = (float*)(ws + OFF_X);
    bf16_t* xb    = (bf16_t*)(ws + OFF_XB);
    bf16_t* h1    = (bf16_t*)(ws + OFF_H1);
    bf16_t* xn    = (bf16_t*)(ws + OFF_XN);
    bf16_t* headb = (bf16_t*)(ws + OFF_HEADB);
    bf16_t* w1b   = (bf16_t*)(ws + OFF_W1B);
    bf16_t* w2b   = (bf16_t*)(ws + OFF_W2B);
    bf16_t* ew1b  = (bf16_t*)(ws + OFF_EW1);
    float*  ent   = (float*)(ws + OFF_ENT);
    float*  cw    = (float*)(ws + OFF_CW);
    float*  hc    = (float*)(ws + OFF_HC);
    float*  bias1 = (float*)(ws + OFF_B1);

    // fused prologue: [cvt3 | embed | prep1]; then merged prep2+prep3
    pro_a_kernel<<<6180, 256, 0, stream>>>(cn_w1, cn_w2, ent_w1, w1b, w2b, ew1b,
                                           tokens, embed_w, pos_w, x, xb,
                                           c_states, ctc_w1, ctc_b1, hc);
    prep23_kernel<<<1, 1024, 0, stream>>>(hc, ctc_w2, ctc_b2, cn_w1, cn_b1, bias1);

    for (int step = 0; step < 6; ++step) {
        float stepf = 1.0f - ((float)step / 6.0f) * 0.8f;
        entropy_mfma<<<128, 256, 0, stream>>>(xb, ew1b, ent_b1, ent_w2, ent_b2, ent);
        // gemm1 + fused softmax (8 leading blocks): 8 + 256 = 264 blocks (R11 config)
        gemm8p<0, 1, 128, 1><<<264, 512, 0, stream>>>(
            xb, 512, w1b, 1536, 1536, 32, 256,
            bias1, h1, 1024, nullptr, nullptr, nullptr,
            ent, base_temp, stepf, cw);
        // gemm2: [8192x1024]x[512x1024]^T, 256x128 tiles -> 128 blocks
        gemm8p<1, 0, 128, 0><<<128, 512, 0, stream>>>(
            h1, 1024, w2b, 1024, 1024, 32, 128,
            cn_b2, xb, 512, cw, x, nullptr,
            nullptr, nullptr, 0.f, nullptr);
    }

    // fused epilogue: [cvt headb | ln]
    epi_kernel<<<18048, 256, 0, stream>>>(head_w, headb, x, ln_g, ln_b, xn);
    // head: [8192x512]x[32000x512]^T, 256x256 tiles -> 4000 blocks
    gemm8p<2, 0, 256, 0><<<4000, 512, 0, stream>>>(
        xn, 512, headb, 512, 512, 32, 4000,
        nullptr, nullptr, 32000, nullptr, nullptr, out,
        nullptr, nullptr, 0.f, nullptr);
}

// Round 16
// 1115.391 us; speedup vs baseline: 1.1432x; 1.0738x over previous
//
#include <hip/hip_runtime.h>
#include <hip/hip_bf16.h>

typedef __hip_bfloat16 bf16_t;
typedef __bf16 bf16x8_t __attribute__((ext_vector_type(8)));
typedef float f32x4_t __attribute__((ext_vector_type(4)));

// ---------------- workspace layout (bytes) ----------------
#define OFF_X     ((size_t)0)          // 8192*512  f32  = 16,777,216
#define OFF_XB    ((size_t)16777216)   // 8192*512  bf16 =  8,388,608
#define OFF_H1    ((size_t)25165824)   // 8192*1024 bf16 = 16,777,216
#define OFF_XN    ((size_t)41943040)   // 8192*512  bf16 =  8,388,608
#define OFF_HEADB ((size_t)50331648)   // 32000*512 bf16 = 32,768,000
#define OFF_W1B   ((size_t)83099648)   // 1024*1536 bf16 =  3,145,728
#define OFF_W2B   ((size_t)86245376)   // 512*1024  bf16 =  1,048,576
#define OFF_EW1   ((size_t)87293952)   // 64*512    bf16 =     65,536
#define OFF_ENT   ((size_t)87359488)   // 8192 f32
#define OFF_CW    ((size_t)87392256)   // 8192 f32
#define OFF_HC    ((size_t)87425024)   // 1024 f32
#define OFF_CC    ((size_t)87429120)   // 512  f32
#define OFF_B1    ((size_t)87431168)   // 1024 f32

__device__ __forceinline__ float gelu_f(float v) {
    return 0.5f * v * (1.0f + erff(v * 0.7071067811865475f));
}

__device__ __forceinline__ void load_lds16(const bf16_t* g, bf16_t* l) {
    __builtin_amdgcn_global_load_lds(
        (const __attribute__((address_space(1))) void*)g,
        (__attribute__((address_space(3))) void*)l, 16, 0, 0);
}

#define BAR()    __builtin_amdgcn_s_barrier()
#define SCHED0() __builtin_amdgcn_sched_barrier(0)
#define LGKM0()  asm volatile("s_waitcnt lgkmcnt(0)" ::: "memory")
#define WAITV0() asm volatile("s_waitcnt vmcnt(0)" ::: "memory")
#define WAITV2() asm volatile("s_waitcnt vmcnt(2)" ::: "memory")
#define WAITV4() asm volatile("s_waitcnt vmcnt(4)" ::: "memory")

// ---------------- f32 -> bf16 convert helper ----------------
__device__ __forceinline__ void cvt_store(const float4 v, __hip_bfloat162* dst) {
    __hip_bfloat162 p0, p1;
    p0.x = __float2bfloat16(v.x); p0.y = __float2bfloat16(v.y);
    p1.x = __float2bfloat16(v.z); p1.y = __float2bfloat16(v.w);
    dst[0] = p0; dst[1] = p1;
}

// ======= fused prologue A: [cvt3 (2080) | embed (4096) | prep1 (4)] = 6180 blocks =======
__global__ void pro_a_kernel(const float* __restrict__ cn_w1, const float* __restrict__ cn_w2,
                             const float* __restrict__ ent_w1,
                             bf16_t* __restrict__ w1b, bf16_t* __restrict__ w2b,
                             bf16_t* __restrict__ ew1b,
                             const int* __restrict__ tokens, const float* __restrict__ ew,
                             const float* __restrict__ pw, float* __restrict__ x,
                             bf16_t* __restrict__ xb,
                             const float* __restrict__ cs, const float* __restrict__ ctc_w1,
                             const float* __restrict__ ctc_b1, float* __restrict__ hc) {
    int bid = blockIdx.x;
    if (bid < 1536) {            // w1b: 1024 rows x first 1536 cols of cn_w1 (ld 2048)
        int idx = bid * 256 + threadIdx.x;
        int k4 = idx % 384;
        int o = idx / 384;
        float4 v = ((const float4*)(cn_w1 + (size_t)o * 2048))[k4];
        cvt_store(v, (__hip_bfloat162*)w1b + idx * 2);
    } else if (bid < 2048) {     // w2b: 512*1024 dense
        int idx = (bid - 1536) * 256 + threadIdx.x;
        float4 v = ((const float4*)cn_w2)[idx];
        cvt_store(v, (__hip_bfloat162*)w2b + idx * 2);
    } else if (bid < 2080) {     // ew1b: 64*512 dense
        int idx = (bid - 2048) * 256 + threadIdx.x;
        float4 v = ((const float4*)ent_w1)[idx];
        cvt_store(v, (__hip_bfloat162*)ew1b + idx * 2);
    } else if (bid < 6176) {     // embed: 8192*128 quads
        int idx = (bid - 2080) * 256 + threadIdx.x;
        int d4 = idx & 127;
        int bt = idx >> 7;
        int t = bt & 1023;
        int tok = tokens[bt];
        float4 e = ((const float4*)(ew + (size_t)tok * 512))[d4];
        float4 p = ((const float4*)(pw + (size_t)t * 512))[d4];
        float4 o = make_float4(e.x + p.x, e.y + p.y, e.z + p.z, e.w + p.w);
        ((float4*)x)[idx] = o;
        __hip_bfloat162 p0, p1;
        p0.x = __float2bfloat16(o.x); p0.y = __float2bfloat16(o.y);
        p1.x = __float2bfloat16(o.z); p1.y = __float2bfloat16(o.w);
        ((__hip_bfloat162*)xb)[idx * 2]     = p0;
        ((__hip_bfloat162*)xb)[idx * 2 + 1] = p1;
    } else {                     // prep1: 1024 outputs
        int o = (bid - 6176) * 256 + threadIdx.x;
        const float* wr = ctc_w1 + (size_t)o * 512;
        float acc = 0.f;
        for (int k = 0; k < 512; k += 4) {
            float4 w4 = *(const float4*)(wr + k);
            float4 a = *(const float4*)(cs + k);
            float4 b = *(const float4*)(cs + 512 + k);
            float4 c = *(const float4*)(cs + 1024 + k);
            float4 d = *(const float4*)(cs + 1536 + k);
            acc += w4.x * (a.x + b.x + c.x + d.x) * 0.25f;
            acc += w4.y * (a.y + b.y + c.y + d.y) * 0.25f;
            acc += w4.z * (a.z + b.z + c.z + d.z) * 0.25f;
            acc += w4.w * (a.w + b.w + c.w + d.w) * 0.25f;
        }
        hc[o] = gelu_f(acc + ctc_b1[o]);
    }
}

__global__ void prep2_kernel(const float* __restrict__ hc, const float* __restrict__ w2,
                             const float* __restrict__ b2, float* __restrict__ cc) {
    int o = blockIdx.x * 256 + threadIdx.x;            // 0..511
    const float* wr = w2 + (size_t)o * 1024;
    float acc = 0.f;
    for (int k = 0; k < 1024; ++k) acc += wr[k] * hc[k];
    cc[o] = acc + b2[o];
}

__global__ void prep3_kernel(const float* __restrict__ cc, const float* __restrict__ cn_w1,
                             const float* __restrict__ cn_b1, float* __restrict__ bias1) {
    int o = blockIdx.x * 256 + threadIdx.x;            // 0..1023
    const float* wr = cn_w1 + (size_t)o * 2048 + 1536;
    float acc = 0.f;
    for (int k = 0; k < 512; ++k) acc += wr[k] * cc[k];
    bias1[o] = acc + cn_b1[o];
}

// ---------------- entropy MLP via MFMA: 16 tokens per wave (R4 exact) ----------------
__global__ __launch_bounds__(256) void entropy_mfma(
        const bf16_t* __restrict__ xb, const bf16_t* __restrict__ w1b,
        const float* __restrict__ b1, const float* __restrict__ w2,
        const float* __restrict__ b2, float* __restrict__ ent) {
    int wave = threadIdx.x >> 6, lane = threadIdx.x & 63;
    int lr = lane & 15, kq = lane >> 4;
    int tok0 = (blockIdx.x * 4 + wave) * 16;
    f32x4_t acc[4] = {};
    const bf16_t* xr = xb + (size_t)(tok0 + lr) * 512 + kq * 8;
    const bf16_t* wr = w1b + (size_t)lr * 512 + kq * 8;
    #pragma unroll 4
    for (int k0 = 0; k0 < 512; k0 += 32) {
        bf16x8_t a = *(const bf16x8_t*)(xr + k0);
        #pragma unroll
        for (int j = 0; j < 4; ++j) {
            bf16x8_t bb = *(const bf16x8_t*)(wr + (size_t)j * 16 * 512 + k0);
            acc[j] = __builtin_amdgcn_mfma_f32_16x16x32_bf16(a, bb, acc[j], 0, 0, 0);
        }
    }
    float p[4];
    #pragma unroll
    for (int r = 0; r < 4; ++r) {
        float s = 0.f;
        #pragma unroll
        for (int j = 0; j < 4; ++j) {
            int n = j * 16 + lr;
            s += gelu_f(acc[j][r] + b1[n]) * w2[n];
        }
        #pragma unroll
        for (int o = 1; o < 16; o <<= 1) s += __shfl_xor(s, o);
        p[r] = s;
    }
    if (lr == 0) {
        float bb = b2[0];
        #pragma unroll
        for (int r = 0; r < 4; ++r) ent[tok0 + kq * 4 + r] = p[r] + bb;
    }
}

// ======= fused epilogue: [cvt headb (16000) | ln (2048)] = 18048 blocks =======
__global__ void epi_kernel(const float* __restrict__ head_w, bf16_t* __restrict__ headb,
                           const float* __restrict__ x, const float* __restrict__ g,
                           const float* __restrict__ b, bf16_t* __restrict__ xn) {
    int bid = blockIdx.x;
    if (bid < 16000) {           // headb convert: 32000*512/4 quads
        int idx = bid * 256 + threadIdx.x;
        float4 v = ((const float4*)head_w)[idx];
        cvt_store(v, (__hip_bfloat162*)headb + idx * 2);
        return;
    }
    // LayerNorm: one wave per token
    int token = (bid - 16000) * 4 + (threadIdx.x >> 6);
    int l = threadIdx.x & 63;
    const float* xr = x + (size_t)token * 512;
    float4 v0 = ((const float4*)xr)[l * 2];
    float4 v1 = ((const float4*)xr)[l * 2 + 1];
    float s = v0.x + v0.y + v0.z + v0.w + v1.x + v1.y + v1.z + v1.w;
    float ss = v0.x * v0.x + v0.y * v0.y + v0.z * v0.z + v0.w * v0.w
             + v1.x * v1.x + v1.y * v1.y + v1.z * v1.z + v1.w * v1.w;
    #pragma unroll
    for (int o = 32; o; o >>= 1) { s += __shfl_xor(s, o); ss += __shfl_xor(ss, o); }
    float mu = s * (1.0f / 512.0f);
    float var = ss * (1.0f / 512.0f) - mu * mu;
    float rs = rsqrtf(var + 1e-5f);
    float4 g0 = ((const float4*)g)[l * 2], g1 = ((const float4*)g)[l * 2 + 1];
    float4 b0 = ((const float4*)b)[l * 2], b1 = ((const float4*)b)[l * 2 + 1];
    bf16_t* op = xn + (size_t)token * 512 + l * 8;
    op[0] = __float2bfloat16((v0.x - mu) * rs * g0.x + b0.x);
    op[1] = __float2bfloat16((v0.y - mu) * rs * g0.y + b0.y);
    op[2] = __float2bfloat16((v0.z - mu) * rs * g0.z + b0.z);
    op[3] = __float2bfloat16((v0.w - mu) * rs * g0.w + b0.w);
    op[4] = __float2bfloat16((v1.x - mu) * rs * g1.x + b1.x);
    op[5] = __float2bfloat16((v1.y - mu) * rs * g1.y + b1.y);
    op[6] = __float2bfloat16((v1.z - mu) * rs * g1.z + b1.z);
    op[7] = __float2bfloat16((v1.w - mu) * rs * g1.w + b1.w);
}

// ================= 8-phase 256xBN bf16 MFMA GEMM (R4-exact; MODE2 nt-stores) =======
// FUSE_SM: blocks [0,8) run the per-batch softmax (R11 refcheck'd variant).
template <int MODE, int ROLL, int BN, int FUSE_SM>
__global__ __launch_bounds__(512, 2) void gemm8p(
    const bf16_t* __restrict__ A, int lda,
    const bf16_t* __restrict__ B, int ldb, int K, int NMT, int ngemm,
    const float* __restrict__ bias,
    bf16_t* __restrict__ out_bf, int ldc,
    const float* __restrict__ cw, float* __restrict__ x,
    float* __restrict__ out_f,
    const float* __restrict__ entp, const float* __restrict__ btp,
    float stepf, float* __restrict__ cwout)
{
    constexpr int JJ = BN / 64;                 // B-frags per wave per kk (4 or 2)
    __shared__ __align__(16) bf16_t As[2][256 * 64];
    __shared__ __align__(16) bf16_t Bs[2][BN * 64];
    __shared__ float sred[8];
    __shared__ float sbc[2];

    const int tid = threadIdx.x;
    const int wave = tid >> 6, lane = tid & 63;

    if (FUSE_SM && (int)blockIdx.x < 8) {
        const float* eb = entp + (size_t)blockIdx.x * 1024;
        float bt = btp[0];
        float sp = (bt > 20.0f) ? bt : log1pf(expf(bt));
        float inv = -1.0f / (sp * stepf);
        float v0 = eb[tid] * inv;
        float v1 = eb[tid + 512] * inv;
        float mx = fmaxf(v0, v1);
        #pragma unroll
        for (int o = 32; o; o >>= 1) mx = fmaxf(mx, __shfl_xor(mx, o));
        if (lane == 0) sred[wave] = mx;
        __syncthreads();
        if (tid < 64) {
            float mm = (tid < 8) ? sred[tid] : -3.4e38f;
            #pragma unroll
            for (int o = 4; o; o >>= 1) mm = fmaxf(mm, __shfl_xor(mm, o));
            if (tid == 0) sbc[0] = mm;
        }
        __syncthreads();
        float M = sbc[0];
        float e0 = expf(v0 - M), e1 = expf(v1 - M);
        float s = e0 + e1;
        #pragma unroll
        for (int o = 32; o; o >>= 1) s += __shfl_xor(s, o);
        if (lane == 0) sred[wave] = s;
        __syncthreads();
        if (tid < 64) {
            float ssum = (tid < 8) ? sred[tid] : 0.f;
            #pragma unroll
            for (int o = 4; o; o >>= 1) ssum += __shfl_xor(ssum, o);
            if (tid == 0) sbc[1] = ssum;
        }
        __syncthreads();
        float S = sbc[1];
        cwout[blockIdx.x * 1024 + tid]       = e0 / S;
        cwout[blockIdx.x * 1024 + tid + 512] = e1 / S;
        return;
    }

    const int NT = K >> 6;
    const int id0 = (int)blockIdx.x - (FUSE_SM ? 8 : 0);
    const int id = (id0 & 7) * (ngemm >> 3) + (id0 >> 3);  // bijective XCD swizzle (ngemm%8==0)
    const int m0 = (id % NMT) * 256;
    const int n0 = (id / NMT) * BN;

    const int wm = (wave >> 2) * 128;
    const int wn = (wave & 3) * (BN / 4);
    const int lr = lane & 15, kq = lane >> 4;

    const int swz0 = (kq)     ^ (lr & 7);
    const int swz1 = (4 + kq) ^ (lr & 7);
    const int eoff0 = lr * 64 + swz0 * 8;
    const int eoff1 = lr * 64 + swz1 * 8;

    const int u0row = tid >> 3;                 // 0..63
    const int u1row = 64 + (tid >> 3);          // 64..127
    const int usl   = tid & 7;
    const int c0 = ((usl ^ (u0row & 7)) * 8);
    const int c1 = ((usl ^ (u1row & 7)) * 8);

    f32x4_t acc[8][JJ] = {};
    bf16x8_t bfr[JJ][2];

    auto stageA = [&](int ktile, int c, int half) {
        const int kbase = ktile << 6;
        const int r0 = m0 + half * 128 + u0row;
        const int r1 = m0 + half * 128 + u1row;
        const bf16_t *g0, *g1;
        if (ROLL) {
            const int seg = kbase >> 9;
            const int kk2 = kbase & 511;
            const int sh = (seg == 0) ? 0 : ((seg == 1) ? 1023 : 1);
            const int s0 = (r0 & ~1023) | (((r0 & 1023) + sh) & 1023);
            const int s1 = (r1 & ~1023) | (((r1 & 1023) + sh) & 1023);
            g0 = A + (size_t)s0 * 512 + kk2 + c0;
            g1 = A + (size_t)s1 * 512 + kk2 + c1;
        } else {
            g0 = A + (size_t)r0 * lda + kbase + c0;
            g1 = A + (size_t)r1 * lda + kbase + c1;
        }
        bf16_t* l = &As[c][half * 128 * 64];
        load_lds16(g0, l + tid * 8);
        load_lds16(g1, l + (tid + 512) * 8);
    };
    auto stageB = [&](int ktile, int c, int half) {
        const int kbase = ktile << 6;
        const int r0 = n0 + half * 128 + u0row;
        const int r1 = n0 + half * 128 + u1row;
        const bf16_t* g0 = B + (size_t)r0 * ldb + kbase + c0;
        const bf16_t* g1 = B + (size_t)r1 * ldb + kbase + c1;
        bf16_t* l = &Bs[c][half * 128 * 64];
        load_lds16(g0, l + tid * 8);
        load_lds16(g1, l + (tid + 512) * 8);
    };

    // ---- prologue: A(0), B(0) resident; B(1) in flight ----
    stageA(0, 0, 0); stageA(0, 0, 1);
    stageB(0, 0, 0); if (BN == 256) stageB(0, 0, 1);
    stageB(1, 1, 0); if (BN == 256) stageB(1, 1, 1);
    if (BN == 256) { WAITV4(); } else { WAITV2(); }
    BAR();

    int cur = 0;
    for (int t = 0; t < NT; ++t) {
        #pragma unroll
        for (int p = 0; p < 4; ++p) {
            bf16x8_t af0k0, af0k1, af1k0, af1k1;
            {
                const int r0 = (wm + 32 * p + lr) * 64;
                const int r1 = (wm + 32 * p + 16 + lr) * 64;
                af0k0 = *(const bf16x8_t*)&As[cur][r0 - lr * 64 + eoff0];
                af0k1 = *(const bf16x8_t*)&As[cur][r0 - lr * 64 + eoff1];
                af1k0 = *(const bf16x8_t*)&As[cur][r1 - lr * 64 + eoff0];
                af1k1 = *(const bf16x8_t*)&As[cur][r1 - lr * 64 + eoff1];
            }
            if (p == 0) {
                #pragma unroll
                for (int j = 0; j < JJ; ++j) {
                    const int rb = (wn + 16 * j) * 64;
                    bfr[j][0] = *(const bf16x8_t*)&Bs[cur][rb + eoff0];
                    bfr[j][1] = *(const bf16x8_t*)&Bs[cur][rb + eoff1];
                }
            }
            if (p == 0 && t + 1 < NT) stageA(t + 1, cur ^ 1, 0);
            if (p == 1 && t + 1 < NT) stageA(t + 1, cur ^ 1, 1);
            if (p == 2 && t + 2 < NT) stageB(t + 2, cur, 0);
            if (p == 3 && BN == 256 && t + 2 < NT) stageB(t + 2, cur, 1);

            BAR();
            LGKM0();
            SCHED0();
            __builtin_amdgcn_s_setprio(1);
            #pragma unroll
            for (int j = 0; j < JJ; ++j) {
                acc[2*p][j]   = __builtin_amdgcn_mfma_f32_16x16x32_bf16(af0k0, bfr[j][0], acc[2*p][j],   0, 0, 0);
                acc[2*p+1][j] = __builtin_amdgcn_mfma_f32_16x16x32_bf16(af1k0, bfr[j][0], acc[2*p+1][j], 0, 0, 0);
            }
            #pragma unroll
            for (int j = 0; j < JJ; ++j) {
                acc[2*p][j]   = __builtin_amdgcn_mfma_f32_16x16x32_bf16(af0k1, bfr[j][1], acc[2*p][j],   0, 0, 0);
                acc[2*p+1][j] = __builtin_amdgcn_mfma_f32_16x16x32_bf16(af1k1, bfr[j][1], acc[2*p+1][j], 0, 0, 0);
            }
            __builtin_amdgcn_s_setprio(0);
            SCHED0();
            if (p == 3) {
                if (t + 2 < NT) { if (BN == 256) { WAITV4(); } else { WAITV2(); } }
                else           { WAITV0(); }
            }
            BAR();
        }
        cur ^= 1;
    }

    // ---- epilogue ----
    #pragma unroll
    for (int i = 0; i < 8; ++i) {
        const int rbase = m0 + wm + i * 16 + kq * 4;   // C/D: row=(lane>>4)*4+reg
        #pragma unroll
        for (int j = 0; j < JJ; ++j) {
            const int gcol = n0 + wn + j * 16 + lr;    // C/D: col=lane&15
            #pragma unroll
            for (int r = 0; r < 4; ++r) {
                const size_t grow = (size_t)(rbase + r);
                float v = acc[i][j][r];
                if (MODE == 0) {
                    v = gelu_f(v + bias[gcol]);
                    out_bf[grow * ldc + gcol] = __float2bfloat16(v);
                } else if (MODE == 1) {
                    v += bias[gcol];
                    float nv = x[grow * ldc + gcol] + v * cw[grow] * 0.3f;
                    x[grow * ldc + gcol] = nv;
                    out_bf[grow * ldc + gcol] = __float2bfloat16(nv);
                } else {
                    // write-once 1.05 GB stream: bypass caches (R10: -79 us)
                    __builtin_nontemporal_store(v, &out_f[grow * ldc + gcol]);
                }
            }
        }
    }
}

extern "C" void kernel_launch(void* const* d_in, const int* in_sizes, int n_in,
                              void* d_out, int out_size, void* d_ws, size_t ws_size,
                              hipStream_t stream) {
    const int*   tokens   = (const int*)d_in[0];
    const float* c_states = (const float*)d_in[1];
    const float* embed_w  = (const float*)d_in[2];
    const float* pos_w    = (const float*)d_in[3];
    const float* cn_w1    = (const float*)d_in[4];
    const float* cn_b1    = (const float*)d_in[5];
    const float* cn_w2    = (const float*)d_in[6];
    const float* cn_b2    = (const float*)d_in[7];
    const float* ent_w1   = (const float*)d_in[8];
    const float* ent_b1   = (const float*)d_in[9];
    const float* ent_w2   = (const float*)d_in[10];
    const float* ent_b2   = (const float*)d_in[11];
    const float* ctc_w1   = (const float*)d_in[12];
    const float* ctc_b1   = (const float*)d_in[13];
    const float* ctc_w2   = (const float*)d_in[14];
    const float* ctc_b2   = (const float*)d_in[15];
    const float* base_temp= (const float*)d_in[16];
    const float* ln_g     = (const float*)d_in[17];
    const float* ln_b     = (const float*)d_in[18];
    const float* head_w   = (const float*)d_in[19];
    float* out = (float*)d_out;

    char* ws = (char*)d_ws;
    float*  x     = (float*)(ws + OFF_X);
    bf16_t* xb    = (bf16_t*)(ws + OFF_XB);
    bf16_t* h1    = (bf16_t*)(ws + OFF_H1);
    bf16_t* xn    = (bf16_t*)(ws + OFF_XN);
    bf16_t* headb = (bf16_t*)(ws + OFF_HEADB);
    bf16_t* w1b   = (bf16_t*)(ws + OFF_W1B);
    bf16_t* w2b   = (bf16_t*)(ws + OFF_W2B);
    bf16_t* ew1b  = (bf16_t*)(ws + OFF_EW1);
    float*  ent   = (float*)(ws + OFF_ENT);
    float*  cw    = (float*)(ws + OFF_CW);
    float*  hc    = (float*)(ws + OFF_HC);
    float*  cc    = (float*)(ws + OFF_CC);
    float*  bias1 = (float*)(ws + OFF_B1);

    // fused prologue: [cvt3 | embed | prep1]; then prep2, prep3 (R11 exact)
    pro_a_kernel<<<6180, 256, 0, stream>>>(cn_w1, cn_w2, ent_w1, w1b, w2b, ew1b,
                                           tokens, embed_w, pos_w, x, xb,
                                           c_states, ctc_w1, ctc_b1, hc);
    prep2_kernel<<<2, 256, 0, stream>>>(hc, ctc_w2, ctc_b2, cc);
    prep3_kernel<<<4, 256, 0, stream>>>(cc, cn_w1, cn_b1, bias1);

    for (int step = 0; step < 6; ++step) {
        float stepf = 1.0f - ((float)step / 6.0f) * 0.8f;
        entropy_mfma<<<128, 256, 0, stream>>>(xb, ew1b, ent_b1, ent_w2, ent_b2, ent);
        // gemm1 + fused softmax (8 leading blocks): 8 + 256 = 264 blocks (R11 config)
        gemm8p<0, 1, 128, 1><<<264, 512, 0, stream>>>(
            xb, 512, w1b, 1536, 1536, 32, 256,
            bias1, h1, 1024, nullptr, nullptr, nullptr,
            ent, base_temp, stepf, cw);
        // gemm2: [8192x1024]x[512x1024]^T, 256x128 tiles -> 128 blocks
        gemm8p<1, 0, 128, 0><<<128, 512, 0, stream>>>(
            h1, 1024, w2b, 1024, 1024, 32, 128,
            cn_b2, xb, 512, cw, x, nullptr,
            nullptr, nullptr, 0.f, nullptr);
    }

    // fused epilogue: [cvt headb | ln]
    epi_kernel<<<18048, 256, 0, stream>>>(head_w, headb, x, ln_g, ln_b, xn);
    // head: [8192x512]x[32000x512]^T, 256x256 tiles -> 4000 blocks
    gemm8p<2, 0, 256, 0><<<4000, 512, 0, stream>>>(
        xn, 512, headb, 512, 512, 32, 4000,
        nullptr, nullptr, 32000, nullptr, nullptr, out,
        nullptr, nullptr, 0.f, nullptr);
}

// Round 17
// 1077.403 us; speedup vs baseline: 1.1835x; 1.0353x over previous
//
#include <hip/hip_runtime.h>
#include <hip/hip_bf16.h>

typedef __hip_bfloat16 bf16_t;
typedef __bf16 bf16x8_t __attribute__((ext_vector_type(8)));
typedef float f32x4_t __attribute__((ext_vector_type(4)));

// ---------------- workspace layout (bytes) ----------------
#define OFF_X     ((size_t)0)          // 8192*512  f32  = 16,777,216
#define OFF_XB    ((size_t)16777216)   // 8192*512  bf16 =  8,388,608
#define OFF_H1    ((size_t)25165824)   // 8192*1024 bf16 = 16,777,216
#define OFF_XN    ((size_t)41943040)   // 8192*512  bf16 =  8,388,608
#define OFF_HEADB ((size_t)50331648)   // 32000*512 bf16 = 32,768,000
#define OFF_W1B   ((size_t)83099648)   // 1024*1536 bf16 =  3,145,728
#define OFF_W2B   ((size_t)86245376)   // 512*1024  bf16 =  1,048,576
#define OFF_EW1   ((size_t)87293952)   // 64*512    bf16 =     65,536
#define OFF_ENT   ((size_t)87359488)   // 8192 f32
#define OFF_CW    ((size_t)87392256)   // 8192 f32
#define OFF_HC    ((size_t)87425024)   // 1024 f32
#define OFF_CC    ((size_t)87429120)   // 512  f32
#define OFF_B1    ((size_t)87431168)   // 1024 f32

__device__ __forceinline__ float gelu_f(float v) {
    return 0.5f * v * (1.0f + erff(v * 0.7071067811865475f));
}

__device__ __forceinline__ void load_lds16(const bf16_t* g, bf16_t* l) {
    __builtin_amdgcn_global_load_lds(
        (const __attribute__((address_space(1))) void*)g,
        (__attribute__((address_space(3))) void*)l, 16, 0, 0);
}

#define BAR()    __builtin_amdgcn_s_barrier()
#define SCHED0() __builtin_amdgcn_sched_barrier(0)
#define LGKM0()  asm volatile("s_waitcnt lgkmcnt(0)" ::: "memory")
#define WAITV0() asm volatile("s_waitcnt vmcnt(0)" ::: "memory")
#define WAITV2() asm volatile("s_waitcnt vmcnt(2)" ::: "memory")
#define WAITV4() asm volatile("s_waitcnt vmcnt(4)" ::: "memory")

// ---------------- f32 -> bf16 convert helper ----------------
__device__ __forceinline__ void cvt_store(const float4 v, __hip_bfloat162* dst) {
    __hip_bfloat162 p0, p1;
    p0.x = __float2bfloat16(v.x); p0.y = __float2bfloat16(v.y);
    p1.x = __float2bfloat16(v.z); p1.y = __float2bfloat16(v.w);
    dst[0] = p0; dst[1] = p1;
}

// ======= fused prologue A: [cvt3 (2080) | embed (4096) | prep1 (4)] = 6180 blocks =======
__global__ void pro_a_kernel(const float* __restrict__ cn_w1, const float* __restrict__ cn_w2,
                             const float* __restrict__ ent_w1,
                             bf16_t* __restrict__ w1b, bf16_t* __restrict__ w2b,
                             bf16_t* __restrict__ ew1b,
                             const int* __restrict__ tokens, const float* __restrict__ ew,
                             const float* __restrict__ pw, float* __restrict__ x,
                             bf16_t* __restrict__ xb,
                             const float* __restrict__ cs, const float* __restrict__ ctc_w1,
                             const float* __restrict__ ctc_b1, float* __restrict__ hc) {
    int bid = blockIdx.x;
    if (bid < 1536) {            // w1b: 1024 rows x first 1536 cols of cn_w1 (ld 2048)
        int idx = bid * 256 + threadIdx.x;
        int k4 = idx % 384;
        int o = idx / 384;
        float4 v = ((const float4*)(cn_w1 + (size_t)o * 2048))[k4];
        cvt_store(v, (__hip_bfloat162*)w1b + idx * 2);
    } else if (bid < 2048) {     // w2b: 512*1024 dense
        int idx = (bid - 1536) * 256 + threadIdx.x;
        float4 v = ((const float4*)cn_w2)[idx];
        cvt_store(v, (__hip_bfloat162*)w2b + idx * 2);
    } else if (bid < 2080) {     // ew1b: 64*512 dense
        int idx = (bid - 2048) * 256 + threadIdx.x;
        float4 v = ((const float4*)ent_w1)[idx];
        cvt_store(v, (__hip_bfloat162*)ew1b + idx * 2);
    } else if (bid < 6176) {     // embed: 8192*128 quads
        int idx = (bid - 2080) * 256 + threadIdx.x;
        int d4 = idx & 127;
        int bt = idx >> 7;
        int t = bt & 1023;
        int tok = tokens[bt];
        float4 e = ((const float4*)(ew + (size_t)tok * 512))[d4];
        float4 p = ((const float4*)(pw + (size_t)t * 512))[d4];
        float4 o = make_float4(e.x + p.x, e.y + p.y, e.z + p.z, e.w + p.w);
        ((float4*)x)[idx] = o;
        __hip_bfloat162 p0, p1;
        p0.x = __float2bfloat16(o.x); p0.y = __float2bfloat16(o.y);
        p1.x = __float2bfloat16(o.z); p1.y = __float2bfloat16(o.w);
        ((__hip_bfloat162*)xb)[idx * 2]     = p0;
        ((__hip_bfloat162*)xb)[idx * 2 + 1] = p1;
    } else {                     // prep1: 1024 outputs
        int o = (bid - 6176) * 256 + threadIdx.x;
        const float* wr = ctc_w1 + (size_t)o * 512;
        float acc = 0.f;
        for (int k = 0; k < 512; k += 4) {
            float4 w4 = *(const float4*)(wr + k);
            float4 a = *(const float4*)(cs + k);
            float4 b = *(const float4*)(cs + 512 + k);
            float4 c = *(const float4*)(cs + 1024 + k);
            float4 d = *(const float4*)(cs + 1536 + k);
            acc += w4.x * (a.x + b.x + c.x + d.x) * 0.25f;
            acc += w4.y * (a.y + b.y + c.y + d.y) * 0.25f;
            acc += w4.z * (a.z + b.z + c.z + d.z) * 0.25f;
            acc += w4.w * (a.w + b.w + c.w + d.w) * 0.25f;
        }
        hc[o] = gelu_f(acc + ctc_b1[o]);
    }
}

// ======= wave-parallel prep2: one wave per output (512 outputs, 128 blocks) =======
__global__ __launch_bounds__(256) void prep2w_kernel(
        const float* __restrict__ hc, const float* __restrict__ w2,
        const float* __restrict__ b2, float* __restrict__ cc) {
    int wave = threadIdx.x >> 6, lane = threadIdx.x & 63;
    int o = blockIdx.x * 4 + wave;              // 0..511
    const float4* wr = (const float4*)(w2 + (size_t)o * 1024);
    const float4* hv = (const float4*)hc;
    float acc = 0.f;
    #pragma unroll
    for (int i = 0; i < 4; ++i) {
        int idx = i * 64 + lane;                // 0..255 float4s
        float4 w = wr[idx], h = hv[idx];
        acc += w.x * h.x + w.y * h.y + w.z * h.z + w.w * h.w;
    }
    #pragma unroll
    for (int off = 32; off; off >>= 1) acc += __shfl_xor(acc, off);
    if (lane == 0) cc[o] = acc + b2[o];
}

// ======= wave-parallel prep3: one wave per output (1024 outputs, 256 blocks) =======
__global__ __launch_bounds__(256) void prep3w_kernel(
        const float* __restrict__ cc, const float* __restrict__ cn_w1,
        const float* __restrict__ cn_b1, float* __restrict__ bias1) {
    int wave = threadIdx.x >> 6, lane = threadIdx.x & 63;
    int o = blockIdx.x * 4 + wave;              // 0..1023
    const float4* wr = (const float4*)(cn_w1 + (size_t)o * 2048 + 1536);
    const float4* cv = (const float4*)cc;
    float acc = 0.f;
    #pragma unroll
    for (int i = 0; i < 2; ++i) {
        int idx = i * 64 + lane;                // 0..127 float4s
        float4 w = wr[idx], c = cv[idx];
        acc += w.x * c.x + w.y * c.y + w.z * c.z + w.w * c.w;
    }
    #pragma unroll
    for (int off = 32; off; off >>= 1) acc += __shfl_xor(acc, off);
    if (lane == 0) bias1[o] = acc + cn_b1[o];
}

// ---------------- entropy MLP via MFMA: 16 tokens per wave (R4 exact) ----------------
__global__ __launch_bounds__(256) void entropy_mfma(
        const bf16_t* __restrict__ xb, const bf16_t* __restrict__ w1b,
        const float* __restrict__ b1, const float* __restrict__ w2,
        const float* __restrict__ b2, float* __restrict__ ent) {
    int wave = threadIdx.x >> 6, lane = threadIdx.x & 63;
    int lr = lane & 15, kq = lane >> 4;
    int tok0 = (blockIdx.x * 4 + wave) * 16;
    f32x4_t acc[4] = {};
    const bf16_t* xr = xb + (size_t)(tok0 + lr) * 512 + kq * 8;
    const bf16_t* wr = w1b + (size_t)lr * 512 + kq * 8;
    #pragma unroll 4
    for (int k0 = 0; k0 < 512; k0 += 32) {
        bf16x8_t a = *(const bf16x8_t*)(xr + k0);
        #pragma unroll
        for (int j = 0; j < 4; ++j) {
            bf16x8_t bb = *(const bf16x8_t*)(wr + (size_t)j * 16 * 512 + k0);
            acc[j] = __builtin_amdgcn_mfma_f32_16x16x32_bf16(a, bb, acc[j], 0, 0, 0);
        }
    }
    float p[4];
    #pragma unroll
    for (int r = 0; r < 4; ++r) {
        float s = 0.f;
        #pragma unroll
        for (int j = 0; j < 4; ++j) {
            int n = j * 16 + lr;
            s += gelu_f(acc[j][r] + b1[n]) * w2[n];
        }
        #pragma unroll
        for (int o = 1; o < 16; o <<= 1) s += __shfl_xor(s, o);
        p[r] = s;
    }
    if (lr == 0) {
        float bb = b2[0];
        #pragma unroll
        for (int r = 0; r < 4; ++r) ent[tok0 + kq * 4 + r] = p[r] + bb;
    }
}

// ======= fused epilogue: [cvt headb (16000) | ln (2048)] = 18048 blocks =======
__global__ void epi_kernel(const float* __restrict__ head_w, bf16_t* __restrict__ headb,
                           const float* __restrict__ x, const float* __restrict__ g,
                           const float* __restrict__ b, bf16_t* __restrict__ xn) {
    int bid = blockIdx.x;
    if (bid < 16000) {           // headb convert: 32000*512/4 quads
        int idx = bid * 256 + threadIdx.x;
        float4 v = ((const float4*)head_w)[idx];
        cvt_store(v, (__hip_bfloat162*)headb + idx * 2);
        return;
    }
    // LayerNorm: one wave per token
    int token = (bid - 16000) * 4 + (threadIdx.x >> 6);
    int l = threadIdx.x & 63;
    const float* xr = x + (size_t)token * 512;
    float4 v0 = ((const float4*)xr)[l * 2];
    float4 v1 = ((const float4*)xr)[l * 2 + 1];
    float s = v0.x + v0.y + v0.z + v0.w + v1.x + v1.y + v1.z + v1.w;
    float ss = v0.x * v0.x + v0.y * v0.y + v0.z * v0.z + v0.w * v0.w
             + v1.x * v1.x + v1.y * v1.y + v1.z * v1.z + v1.w * v1.w;
    #pragma unroll
    for (int o = 32; o; o >>= 1) { s += __shfl_xor(s, o); ss += __shfl_xor(ss, o); }
    float mu = s * (1.0f / 512.0f);
    float var = ss * (1.0f / 512.0f) - mu * mu;
    float rs = rsqrtf(var + 1e-5f);
    float4 g0 = ((const float4*)g)[l * 2], g1 = ((const float4*)g)[l * 2 + 1];
    float4 b0 = ((const float4*)b)[l * 2], b1 = ((const float4*)b)[l * 2 + 1];
    bf16_t* op = xn + (size_t)token * 512 + l * 8;
    op[0] = __float2bfloat16((v0.x - mu) * rs * g0.x + b0.x);
    op[1] = __float2bfloat16((v0.y - mu) * rs * g0.y + b0.y);
    op[2] = __float2bfloat16((v0.z - mu) * rs * g0.z + b0.z);
    op[3] = __float2bfloat16((v0.w - mu) * rs * g0.w + b0.w);
    op[4] = __float2bfloat16((v1.x - mu) * rs * g1.x + b1.x);
    op[5] = __float2bfloat16((v1.y - mu) * rs * g1.y + b1.y);
    op[6] = __float2bfloat16((v1.z - mu) * rs * g1.z + b1.z);
    op[7] = __float2bfloat16((v1.w - mu) * rs * g1.w + b1.w);
}

// ================= 8-phase 256xBN bf16 MFMA GEMM (R4-exact; MODE2 nt-stores) =======
// FUSE_SM: blocks [0,8) run the per-batch softmax (R11 refcheck'd variant).
template <int MODE, int ROLL, int BN, int FUSE_SM>
__global__ __launch_bounds__(512, 2) void gemm8p(
    const bf16_t* __restrict__ A, int lda,
    const bf16_t* __restrict__ B, int ldb, int K, int NMT, int ngemm,
    const float* __restrict__ bias,
    bf16_t* __restrict__ out_bf, int ldc,
    const float* __restrict__ cw, float* __restrict__ x,
    float* __restrict__ out_f,
    const float* __restrict__ entp, const float* __restrict__ btp,
    float stepf, float* __restrict__ cwout)
{
    constexpr int JJ = BN / 64;                 // B-frags per wave per kk (4 or 2)
    __shared__ __align__(16) bf16_t As[2][256 * 64];
    __shared__ __align__(16) bf16_t Bs[2][BN * 64];
    __shared__ float sred[8];
    __shared__ float sbc[2];

    const int tid = threadIdx.x;
    const int wave = tid >> 6, lane = tid & 63;

    if (FUSE_SM && (int)blockIdx.x < 8) {
        const float* eb = entp + (size_t)blockIdx.x * 1024;
        float bt = btp[0];
        float sp = (bt > 20.0f) ? bt : log1pf(expf(bt));
        float inv = -1.0f / (sp * stepf);
        float v0 = eb[tid] * inv;
        float v1 = eb[tid + 512] * inv;
        float mx = fmaxf(v0, v1);
        #pragma unroll
        for (int o = 32; o; o >>= 1) mx = fmaxf(mx, __shfl_xor(mx, o));
        if (lane == 0) sred[wave] = mx;
        __syncthreads();
        if (tid < 64) {
            float mm = (tid < 8) ? sred[tid] : -3.4e38f;
            #pragma unroll
            for (int o = 4; o; o >>= 1) mm = fmaxf(mm, __shfl_xor(mm, o));
            if (tid == 0) sbc[0] = mm;
        }
        __syncthreads();
        float M = sbc[0];
        float e0 = expf(v0 - M), e1 = expf(v1 - M);
        float s = e0 + e1;
        #pragma unroll
        for (int o = 32; o; o >>= 1) s += __shfl_xor(s, o);
        if (lane == 0) sred[wave] = s;
        __syncthreads();
        if (tid < 64) {
            float ssum = (tid < 8) ? sred[tid] : 0.f;
            #pragma unroll
            for (int o = 4; o; o >>= 1) ssum += __shfl_xor(ssum, o);
            if (tid == 0) sbc[1] = ssum;
        }
        __syncthreads();
        float S = sbc[1];
        cwout[blockIdx.x * 1024 + tid]       = e0 / S;
        cwout[blockIdx.x * 1024 + tid + 512] = e1 / S;
        return;
    }

    const int NT = K >> 6;
    const int id0 = (int)blockIdx.x - (FUSE_SM ? 8 : 0);
    const int id = (id0 & 7) * (ngemm >> 3) + (id0 >> 3);  // bijective XCD swizzle (ngemm%8==0)
    const int m0 = (id % NMT) * 256;
    const int n0 = (id / NMT) * BN;

    const int wm = (wave >> 2) * 128;
    const int wn = (wave & 3) * (BN / 4);
    const int lr = lane & 15, kq = lane >> 4;

    const int swz0 = (kq)     ^ (lr & 7);
    const int swz1 = (4 + kq) ^ (lr & 7);
    const int eoff0 = lr * 64 + swz0 * 8;
    const int eoff1 = lr * 64 + swz1 * 8;

    const int u0row = tid >> 3;                 // 0..63
    const int u1row = 64 + (tid >> 3);          // 64..127
    const int usl   = tid & 7;
    const int c0 = ((usl ^ (u0row & 7)) * 8);
    const int c1 = ((usl ^ (u1row & 7)) * 8);

    f32x4_t acc[8][JJ] = {};
    bf16x8_t bfr[JJ][2];

    auto stageA = [&](int ktile, int c, int half) {
        const int kbase = ktile << 6;
        const int r0 = m0 + half * 128 + u0row;
        const int r1 = m0 + half * 128 + u1row;
        const bf16_t *g0, *g1;
        if (ROLL) {
            const int seg = kbase >> 9;
            const int kk2 = kbase & 511;
            const int sh = (seg == 0) ? 0 : ((seg == 1) ? 1023 : 1);
            const int s0 = (r0 & ~1023) | (((r0 & 1023) + sh) & 1023);
            const int s1 = (r1 & ~1023) | (((r1 & 1023) + sh) & 1023);
            g0 = A + (size_t)s0 * 512 + kk2 + c0;
            g1 = A + (size_t)s1 * 512 + kk2 + c1;
        } else {
            g0 = A + (size_t)r0 * lda + kbase + c0;
            g1 = A + (size_t)r1 * lda + kbase + c1;
        }
        bf16_t* l = &As[c][half * 128 * 64];
        load_lds16(g0, l + tid * 8);
        load_lds16(g1, l + (tid + 512) * 8);
    };
    auto stageB = [&](int ktile, int c, int half) {
        const int kbase = ktile << 6;
        const int r0 = n0 + half * 128 + u0row;
        const int r1 = n0 + half * 128 + u1row;
        const bf16_t* g0 = B + (size_t)r0 * ldb + kbase + c0;
        const bf16_t* g1 = B + (size_t)r1 * ldb + kbase + c1;
        bf16_t* l = &Bs[c][half * 128 * 64];
        load_lds16(g0, l + tid * 8);
        load_lds16(g1, l + (tid + 512) * 8);
    };

    // ---- prologue: A(0), B(0) resident; B(1) in flight ----
    stageA(0, 0, 0); stageA(0, 0, 1);
    stageB(0, 0, 0); if (BN == 256) stageB(0, 0, 1);
    stageB(1, 1, 0); if (BN == 256) stageB(1, 1, 1);
    if (BN == 256) { WAITV4(); } else { WAITV2(); }
    BAR();

    int cur = 0;
    for (int t = 0; t < NT; ++t) {
        #pragma unroll
        for (int p = 0; p < 4; ++p) {
            bf16x8_t af0k0, af0k1, af1k0, af1k1;
            {
                const int r0 = (wm + 32 * p + lr) * 64;
                const int r1 = (wm + 32 * p + 16 + lr) * 64;
                af0k0 = *(const bf16x8_t*)&As[cur][r0 - lr * 64 + eoff0];
                af0k1 = *(const bf16x8_t*)&As[cur][r0 - lr * 64 + eoff1];
                af1k0 = *(const bf16x8_t*)&As[cur][r1 - lr * 64 + eoff0];
                af1k1 = *(const bf16x8_t*)&As[cur][r1 - lr * 64 + eoff1];
            }
            if (p == 0) {
                #pragma unroll
                for (int j = 0; j < JJ; ++j) {
                    const int rb = (wn + 16 * j) * 64;
                    bfr[j][0] = *(const bf16x8_t*)&Bs[cur][rb + eoff0];
                    bfr[j][1] = *(const bf16x8_t*)&Bs[cur][rb + eoff1];
                }
            }
            if (p == 0 && t + 1 < NT) stageA(t + 1, cur ^ 1, 0);
            if (p == 1 && t + 1 < NT) stageA(t + 1, cur ^ 1, 1);
            if (p == 2 && t + 2 < NT) stageB(t + 2, cur, 0);
            if (p == 3 && BN == 256 && t + 2 < NT) stageB(t + 2, cur, 1);

            BAR();
            LGKM0();
            SCHED0();
            __builtin_amdgcn_s_setprio(1);
            #pragma unroll
            for (int j = 0; j < JJ; ++j) {
                acc[2*p][j]   = __builtin_amdgcn_mfma_f32_16x16x32_bf16(af0k0, bfr[j][0], acc[2*p][j],   0, 0, 0);
                acc[2*p+1][j] = __builtin_amdgcn_mfma_f32_16x16x32_bf16(af1k0, bfr[j][0], acc[2*p+1][j], 0, 0, 0);
            }
            #pragma unroll
            for (int j = 0; j < JJ; ++j) {
                acc[2*p][j]   = __builtin_amdgcn_mfma_f32_16x16x32_bf16(af0k1, bfr[j][1], acc[2*p][j],   0, 0, 0);
                acc[2*p+1][j] = __builtin_amdgcn_mfma_f32_16x16x32_bf16(af1k1, bfr[j][1], acc[2*p+1][j], 0, 0, 0);
            }
            __builtin_amdgcn_s_setprio(0);
            SCHED0();
            if (p == 3) {
                if (t + 2 < NT) { if (BN == 256) { WAITV4(); } else { WAITV2(); } }
                else           { WAITV0(); }
            }
            BAR();
        }
        cur ^= 1;
    }

    // ---- epilogue ----
    #pragma unroll
    for (int i = 0; i < 8; ++i) {
        const int rbase = m0 + wm + i * 16 + kq * 4;   // C/D: row=(lane>>4)*4+reg
        #pragma unroll
        for (int j = 0; j < JJ; ++j) {
            const int gcol = n0 + wn + j * 16 + lr;    // C/D: col=lane&15
            #pragma unroll
            for (int r = 0; r < 4; ++r) {
                const size_t grow = (size_t)(rbase + r);
                float v = acc[i][j][r];
                if (MODE == 0) {
                    v = gelu_f(v + bias[gcol]);
                    out_bf[grow * ldc + gcol] = __float2bfloat16(v);
                } else if (MODE == 1) {
                    v += bias[gcol];
                    float nv = x[grow * ldc + gcol] + v * cw[grow] * 0.3f;
                    x[grow * ldc + gcol] = nv;
                    out_bf[grow * ldc + gcol] = __float2bfloat16(nv);
                } else {
                    // write-once 1.05 GB stream: bypass caches (R10: -79 us)
                    __builtin_nontemporal_store(v, &out_f[grow * ldc + gcol]);
                }
            }
        }
    }
}

extern "C" void kernel_launch(void* const* d_in, const int* in_sizes, int n_in,
                              void* d_out, int out_size, void* d_ws, size_t ws_size,
                              hipStream_t stream) {
    const int*   tokens   = (const int*)d_in[0];
    const float* c_states = (const float*)d_in[1];
    const float* embed_w  = (const float*)d_in[2];
    const float* pos_w    = (const float*)d_in[3];
    const float* cn_w1    = (const float*)d_in[4];
    const float* cn_b1    = (const float*)d_in[5];
    const float* cn_w2    = (const float*)d_in[6];
    const float* cn_b2    = (const float*)d_in[7];
    const float* ent_w1   = (const float*)d_in[8];
    const float* ent_b1   = (const float*)d_in[9];
    const float* ent_w2   = (const float*)d_in[10];
    const float* ent_b2   = (const float*)d_in[11];
    const float* ctc_w1   = (const float*)d_in[12];
    const float* ctc_b1   = (const float*)d_in[13];
    const float* ctc_w2   = (const float*)d_in[14];
    const float* ctc_b2   = (const float*)d_in[15];
    const float* base_temp= (const float*)d_in[16];
    const float* ln_g     = (const float*)d_in[17];
    const float* ln_b     = (const float*)d_in[18];
    const float* head_w   = (const float*)d_in[19];
    float* out = (float*)d_out;

    char* ws = (char*)d_ws;
    float*  x     = (float*)(ws + OFF_X);
    bf16_t* xb    = (bf16_t*)(ws + OFF_XB);
    bf16_t* h1    = (bf16_t*)(ws + OFF_H1);
    bf16_t* xn    = (bf16_t*)(ws + OFF_XN);
    bf16_t* headb = (bf16_t*)(ws + OFF_HEADB);
    bf16_t* w1b   = (bf16_t*)(ws + OFF_W1B);
    bf16_t* w2b   = (bf16_t*)(ws + OFF_W2B);
    bf16_t* ew1b  = (bf16_t*)(ws + OFF_EW1);
    float*  ent   = (float*)(ws + OFF_ENT);
    float*  cw    = (float*)(ws + OFF_CW);
    float*  hc    = (float*)(ws + OFF_HC);
    float*  cc    = (float*)(ws + OFF_CC);
    float*  bias1 = (float*)(ws + OFF_B1);

    // fused prologue: [cvt3 | embed | prep1]; then wave-parallel prep2, prep3
    pro_a_kernel<<<6180, 256, 0, stream>>>(cn_w1, cn_w2, ent_w1, w1b, w2b, ew1b,
                                           tokens, embed_w, pos_w, x, xb,
                                           c_states, ctc_w1, ctc_b1, hc);
    prep2w_kernel<<<128, 256, 0, stream>>>(hc, ctc_w2, ctc_b2, cc);
    prep3w_kernel<<<256, 256, 0, stream>>>(cc, cn_w1, cn_b1, bias1);

    for (int step = 0; step < 6; ++step) {
        float stepf = 1.0f - ((float)step / 6.0f) * 0.8f;
        entropy_mfma<<<128, 256, 0, stream>>>(xb, ew1b, ent_b1, ent_w2, ent_b2, ent);
        // gemm1 + fused softmax (8 leading blocks): 8 + 256 = 264 blocks (R11 config)
        gemm8p<0, 1, 128, 1><<<264, 512, 0, stream>>>(
            xb, 512, w1b, 1536, 1536, 32, 256,
            bias1, h1, 1024, nullptr, nullptr, nullptr,
            ent, base_temp, stepf, cw);
        // gemm2: [8192x1024]x[512x1024]^T, 256x128 tiles -> 128 blocks
        gemm8p<1, 0, 128, 0><<<128, 512, 0, stream>>>(
            h1, 1024, w2b, 1024, 1024, 32, 128,
            cn_b2, xb, 512, cw, x, nullptr,
            nullptr, nullptr, 0.f, nullptr);
    }

    // fused epilogue: [cvt headb | ln]
    epi_kernel<<<18048, 256, 0, stream>>>(head_w, headb, x, ln_g, ln_b, xn);
    // head: [8192x512]x[32000x512]^T, 256x256 tiles -> 4000 blocks
    gemm8p<2, 0, 256, 0><<<4000, 512, 0, stream>>>(
        xn, 512, headb, 512, 512, 32, 4000,
        nullptr, nullptr, 32000, nullptr, nullptr, out,
        nullptr, nullptr, 0.f, nullptr);
}